// Round 4
// baseline (543.300 us; speedup 1.0000x reference)
//
#include <hip/hip_runtime.h>
#include <hip/hip_bf16.h>

typedef __hip_bfloat16 bf16;
typedef unsigned short ushort_t;
typedef __bf16 bf16x8 __attribute__((ext_vector_type(8)));
typedef float  f32x4  __attribute__((ext_vector_type(4)));

#define HW    4096
#define NB    8
#define KSTR  4160     // padded token count for k/pos; token 4096 = dustbin
#define NTOK  32768    // NB*HW
#define PROWS 64       // padded pos channel rows (34 real + ones@34 + zeros, 48..63 slack)
#define QSCALE 0.0901684400557f   // (1/16) * log2(e): folds exp->exp2

#define KT3   32       // attn k-tile tokens (pipelined)
#define NKT3  130      // KSTR / KT3

__device__ __forceinline__ float lde(const void* p, size_t i, int f32f) {
    return f32f ? ((const float*)p)[i] : (float)((const bf16*)p)[i];
}
__device__ __forceinline__ ushort_t f2bu(float f){ union { __bf16 b; ushort_t u; } cv; cv.b = (__bf16)f; return cv.u; }

__device__ __forceinline__ void async_cp16(const void* g, void* l) {
    __builtin_amdgcn_global_load_lds(
        (const __attribute__((address_space(1))) unsigned int*)g,
        (__attribute__((address_space(3))) unsigned int*)l, 16, 0, 0);
}

// ---------------------------------------------------------------------------
// dtype detector: flag=1 if inputs are float32, 0 if bf16.
// ---------------------------------------------------------------------------
__global__ void detect_kernel(const ushort_t* xb, int* flag)
{
    __shared__ int cnt;
    const int t = threadIdx.x;
    if (t == 0) cnt = 0;
    __syncthreads();
    ushort_t h = xb[2*t];
    int e = (h >> 7) & 0xFF;
    if (e >= 133) atomicAdd(&cnt, 1);
    __syncthreads();
    if (t == 0) *flag = (cnt > 8) ? 1 : 0;
}

// ---------------------------------------------------------------------------
// prep: weights/biases -> bf16/f32 ws copies; dw taps transposed; pos fixed
// rows (mesh 32/33, ones 34, zeros 35..47, dustbin col 4096, ztail 4097+).
// ---------------------------------------------------------------------------
struct WsPtrs {
    bf16 *fw1t, *fw2t, *pwt, *pgw1t, *pgw2t, *dwt, *pos;
    float *posw, *fb1, *fb2, *pwb, *pgb1, *pgb2, *dwb;
};

__global__ __launch_bounds__(256) void prep_kernel(
    const void* fus_w1, const void* fus_w2, const void* pw_w,
    const void* pg_w1, const void* pg_w2, const void* dw_w,
    const void* fus_b1, const void* fus_b2, const void* pw_b,
    const void* pg_b1, const void* pg_b2, const void* dw_b,
    const void* dpos, WsPtrs W, const int* flag)
{
    const int f = *flag;
    const long n_w1 = 98304, n_w2 = 65536, n_pw = 65536, n_g1 = 16384, n_g2 = 4096;
    const long n_posw = 256, n_dwt = 2304;
    const long n_b = 256, n_gb1 = 128, n_gb2 = 32;
    const long n_mesh = 65536;            // rows 32/33, tok 0..4095
    const long n_pad  = 8L*14*KSTR;       // rows 34..47 (34=ones) all cols
    const long n_dust = 272;              // rows 0..33 col 4096
    const long n_zt   = 8L*34*63;         // rows 0..33 cols 4097..4159
    const long total = n_w1+n_w2+n_pw+n_g1+n_g2+n_posw+n_dwt
                     + 3*n_b + n_gb1 + n_gb2 + n_b + n_mesh + n_pad + n_dust + n_zt;

    for (long i = blockIdx.x*256L + threadIdx.x; i < total; i += gridDim.x*256L) {
        long j = i;
        if (j < n_w1) { W.fw1t[j] = __float2bfloat16(lde(fus_w1, j, f)); continue; } j -= n_w1;
        if (j < n_w2) { W.fw2t[j] = __float2bfloat16(lde(fus_w2, j, f)); continue; } j -= n_w2;
        if (j < n_pw) { W.pwt[j]  = __float2bfloat16(lde(pw_w,  j, f)); continue; } j -= n_pw;
        if (j < n_g1) { W.pgw1t[j] = __float2bfloat16(lde(pg_w1, (j>>7)*130 + 2 + (j&127), f)); continue; } j -= n_g1;
        if (j < n_g2) { W.pgw2t[j] = __float2bfloat16(lde(pg_w2, j, f)); continue; } j -= n_g2;
        if (j < n_posw) { W.posw[j] = lde(pg_w1, (j>>1)*130 + (j&1), f); continue; } j -= n_posw;
        if (j < n_dwt) { W.dwt[j] = __float2bfloat16(lde(dw_w, (j&255)*9 + (j>>8), f)); continue; } j -= n_dwt;
        if (j < n_b)   { W.fb1[j] = lde(fus_b1, j, f); continue; } j -= n_b;
        if (j < n_b)   { W.fb2[j] = lde(fus_b2, j, f); continue; } j -= n_b;
        if (j < n_b)   { W.pwb[j] = lde(pw_b, j, f); continue; } j -= n_b;
        if (j < n_gb1) { W.pgb1[j] = lde(pg_b1, j, f); continue; } j -= n_gb1;
        if (j < n_gb2) { W.pgb2[j] = lde(pg_b2, j, f); continue; } j -= n_gb2;
        if (j < n_b)   { W.dwb[j] = lde(dw_b, j, f); continue; } j -= n_b;
        if (j < n_mesh) {
            long b = j >> 13; int rr = (int)((j>>12)&1); int tok = (int)(j & 4095);
            float v = rr ? (-1.f + 2.f*(float)((tok>>6)&63)/63.f)
                         : (-1.f + 2.f*(float)(tok&63)/63.f);
            W.pos[((size_t)b*PROWS + 32 + rr)*KSTR + tok] = __float2bfloat16(v);
            continue;
        } j -= n_mesh;
        if (j < n_pad) {
            long b = j / (14L*KSTR); long rem = j % (14L*KSTR);
            int row = 34 + (int)(rem / KSTR); int tok = (int)(rem % KSTR);
            W.pos[((size_t)b*PROWS + row)*KSTR + tok] = __float2bfloat16(row == 34 ? 1.f : 0.f);
            continue;
        } j -= n_pad;
        if (j < n_dust) {
            long b = j / 34; int ch = (int)(j % 34);
            W.pos[((size_t)b*PROWS + ch)*KSTR + 4096] = __float2bfloat16(lde(dpos, ch, f));
            continue;
        } j -= n_dust;
        { long b = j / (34*63); long rem = j % (34*63);
          int ch = (int)(rem / 63); int cc = (int)(rem % 63);
          W.pos[((size_t)b*PROWS + ch)*KSTR + 4097 + cc] = __float2bfloat16(0.f); }
    }
}

// ---------------------------------------------------------------------------
// transpose: ch-major [b][C][4096] (ext dtype) -> token-major bf16 rows of
// in_xy [32768][384] (main -> cols 0..255, feat -> cols 256..383).
// ---------------------------------------------------------------------------
__global__ __launch_bounds__(256) void transpose_kernel(
    const void* main_src, const void* feat_src, bf16* __restrict__ dst, const int* flag)
{
    __shared__ float Tt[64*65];
    const int t = threadIdx.x;
    const int p0 = blockIdx.x * 64;
    const int cht = blockIdx.y;
    const int b = blockIdx.z;
    const int f = *flag;

    const void* src; int ch0, srcC, dc0;
    if (cht < 4) { src = main_src; ch0 = cht*64; srcC = 256; dc0 = ch0; }
    else         { src = feat_src; ch0 = (cht-4)*64; srcC = 128; dc0 = 256 + (cht-4)*64; }

    const int p = t & 63, cq = t >> 6;
    #pragma unroll
    for (int e = 0; e < 16; ++e) {
        int c = e*4 + cq;
        Tt[p*65 + c] = lde(src, ((size_t)b*srcC + ch0 + c)*HW + p0 + p, f);
    }
    __syncthreads();
    const int pr = t >> 2, cs = (t & 3) * 16;
    union { uint4 u4[2]; ushort_t us[16]; } pk;
    #pragma unroll
    for (int u = 0; u < 16; ++u) pk.us[u] = f2bu(Tt[pr*65 + cs + u]);
    ushort_t* op = (ushort_t*)dst + ((size_t)b*HW + p0 + pr)*384 + dc0 + cs;
    *(uint4*)op = pk.u4[0];
    *((uint4*)op + 1) = pk.u4[1];
}

// ---------------------------------------------------------------------------
// MFMA GEMM, token-major. A [NTOK][sa] bf16 (k-contig), Bw [M][ldb] bf16.
// OMODE 0: out[tok*sm + m]; 2: out[(tok + 64*(tok>>12))*sm + m] (k_t);
// 1: pos-mode out[((tok>>12)*PROWS + m)*KSTR + tok&4095].
// ---------------------------------------------------------------------------
template<int MT, bool RELU, bool POSEPI, int OMODE>
__global__ __launch_bounds__(256) void gemm_mfma(
    const bf16* __restrict__ A, int sa,
    const bf16* __restrict__ Bw, int ldb,
    const float* __restrict__ bias, const float* __restrict__ posw,
    bf16* __restrict__ out, int sm, int K, float oscale)
{
    const int t = threadIdx.x;
    const int w = t >> 6, lane = t & 63;
    const int n = lane & 15, quad = lane >> 4;
    const int p0 = blockIdx.x * 128;
    const int m0 = blockIdx.y * (MT*16);
    const int rowbase = p0 + w*32;

    f32x4 acc[2][MT];
    #pragma unroll
    for (int pt = 0; pt < 2; ++pt)
        #pragma unroll
        for (int mt = 0; mt < MT; ++mt) acc[pt][mt] = (f32x4){0.f,0.f,0.f,0.f};

    for (int k0 = 0; k0 < K; k0 += 32) {
        bf16x8 ap[2];
        #pragma unroll
        for (int pt = 0; pt < 2; ++pt)
            ap[pt] = *(const bf16x8*)&A[(size_t)(rowbase + pt*16 + n)*sa + k0 + quad*8];
        #pragma unroll
        for (int mt = 0; mt < MT; ++mt) {
            bf16x8 bw = *(const bf16x8*)&Bw[(size_t)(m0 + mt*16 + n)*ldb + k0 + quad*8];
            acc[0][mt] = __builtin_amdgcn_mfma_f32_16x16x32_bf16(ap[0], bw, acc[0][mt], 0, 0, 0);
            acc[1][mt] = __builtin_amdgcn_mfma_f32_16x16x32_bf16(ap[1], bw, acc[1][mt], 0, 0, 0);
        }
    }

    #pragma unroll
    for (int mt = 0; mt < MT; ++mt) {
        const int m = m0 + mt*16 + n;
        const float bi = bias[m];
        float w0 = 0.f, w1 = 0.f;
        if (POSEPI) { w0 = posw[m*2]; w1 = posw[m*2 + 1]; }
        #pragma unroll
        for (int pt = 0; pt < 2; ++pt) {
            const int tokb = rowbase + pt*16 + quad*4;
            if (OMODE == 1) {
                union { uint2 u2; ushort_t us[4]; } pk;
                #pragma unroll
                for (int r = 0; r < 4; ++r) {
                    float v = acc[pt][mt][r] + bi;
                    if (RELU) v = fmaxf(v, 0.f);
                    pk.us[r] = f2bu(v * oscale);
                }
                size_t oi = ((size_t)(tokb >> 12)*PROWS + m)*KSTR + (tokb & 4095);
                *(uint2*)((ushort_t*)out + oi) = pk.u2;
            } else {
                #pragma unroll
                for (int r = 0; r < 4; ++r) {
                    int tok = tokb + r;
                    float v = acc[pt][mt][r] + bi;
                    if (POSEPI) {
                        float gx1 = 2.f * (float)(tok & 63) / 63.f;
                        float gy1 = 2.f * (float)((tok >> 6) & 63) / 63.f;
                        v += w0*gx1 + w1*gy1;
                    }
                    if (RELU) v = fmaxf(v, 0.f);
                    v *= oscale;
                    size_t row = (OMODE == 2) ? (size_t)tok + 64*(size_t)(tok >> 12) : (size_t)tok;
                    out[row*sm + m] = __float2bfloat16(v);
                }
            }
        }
    }
}

// ---------------------------------------------------------------------------
// depthwise 3x3 SAME + bias, token-major bf16.
// ---------------------------------------------------------------------------
__global__ __launch_bounds__(256) void dw_kernel(
    const bf16* __restrict__ in, const bf16* __restrict__ dwt,
    const float* __restrict__ dwb, bf16* __restrict__ out)
{
    const int t = threadIdx.x;
    const int tok = blockIdx.x*8 + (t >> 5);
    const int c8 = (t & 31) * 8;
    const int b = tok >> 12, p = tok & 4095;
    const int i = p >> 6, j = p & 63;

    float acc[8];
    #pragma unroll
    for (int u = 0; u < 8; ++u) acc[u] = dwb[c8 + u];

    #pragma unroll
    for (int di = 0; di < 3; ++di) {
        int ii = i + di - 1;
        if (ii < 0 || ii >= 64) continue;
        #pragma unroll
        for (int dj = 0; dj < 3; ++dj) {
            int jj = j + dj - 1;
            if (jj < 0 || jj >= 64) continue;
            int tok2 = (b << 12) + ii*64 + jj;
            bf16x8 xv = *(const bf16x8*)&in[(size_t)tok2*256 + c8];
            bf16x8 wv = *(const bf16x8*)&dwt[(di*3 + dj)*256 + c8];
            #pragma unroll
            for (int u = 0; u < 8; ++u) acc[u] += (float)xv[u] * (float)wv[u];
        }
    }
    union { uint4 u4; ushort_t us[8]; } pk;
    #pragma unroll
    for (int u = 0; u < 8; ++u) pk.us[u] = f2bu(acc[u]);
    *(uint4*)((ushort_t*)out + (size_t)tok*256 + c8) = pk.u4;
}

// ---------------------------------------------------------------------------
// fill_late: k dustbin token row.
// ---------------------------------------------------------------------------
__global__ __launch_bounds__(256) void fill_late_kernel(
    const void* dvec, bf16* __restrict__ k_t, const int* flag)
{
    const int b = blockIdx.x, t = threadIdx.x;
    k_t[((size_t)b*KSTR + 4096)*256 + t] = __float2bfloat16(lde(dvec, t, *flag));
}

// ---------------------------------------------------------------------------
// MFMA flash attention v5: LDS-bandwidth-optimized.
// Round-3 finding: v4 was LDS-read-BW-bound (every 16-q-row wave read the
// whole K tile: 8 waves x 19.5 KB/iter = 156 KB/CU/iter > 112 B/cyc ceiling).
// v5: 2 waves x 32 q-rows each (2 A-fragments/wave) -> each bk/bp LDS read
// feeds 2 MFMAs; per-CU LDS traffic per FLOP halves. 128 thr/block, grid 512,
// triple-buffered K/pos staged via global_load_lds, one raw s_barrier per
// tile with counted s_waitcnt vmcnt(10) (= the 10 just-issued next-tile
// loads stay in flight across the barrier).
// No-max softmax via exp2 (log2e pre-folded into q); l via ones-row (ch 34).
// b = bid&7 pins each batch to one XCD (K+pos working set L2-resident).
// ---------------------------------------------------------------------------
__global__ __launch_bounds__(128) void attn_kernel(
    const bf16* __restrict__ q_t, const bf16* __restrict__ k_t,
    const bf16* __restrict__ pos, void* outv, const int* flag)
{
    __shared__ __align__(16) __bf16 Ks[3*1024*8];   // 3 bufs x (32 tok x 32 chunks x 16B), swizzled
    __shared__ __align__(16) __bf16 posb[3*256*8];  // 3 bufs x (64 rows x 4 chunks x 16B), linear
    __shared__ __align__(16) __bf16 Pb[64*40];      // P [q][k], stride 40

    const int t = threadIdx.x;
    const int w = t >> 6, lane = t & 63;            // w in {0,1}
    const int n = lane & 15, quad = lane >> 4;
    const int bid = blockIdx.x;
    const int b = bid & 7;          // batch == XCD id (round-robin dispatch)
    const int qt = bid >> 3;

    // Q fragments: 2 x 16 q-rows per wave (rows w*32+f*16 .. +15)
    bf16x8 aq[2][8];
    #pragma unroll
    for (int f = 0; f < 2; ++f) {
        size_t qrow = (size_t)b*HW + qt*64 + w*32 + f*16 + n;
        #pragma unroll
        for (int c = 0; c < 8; ++c)
            aq[f][c] = *(const bf16x8*)&q_t[qrow*256 + c*32 + quad*8];
    }

    f32x4 pacc[2][3];
    #pragma unroll
    for (int f = 0; f < 2; ++f)
        #pragma unroll
        for (int ct = 0; ct < 3; ++ct) pacc[f][ct] = (f32x4){0.f,0.f,0.f,0.f};

    const ushort_t* ksrc0 = (const ushort_t*)k_t + (size_t)b*KSTR*256;
    const ushort_t* psrc0 = (const ushort_t*)pos + (size_t)b*PROWS*KSTR;
    const int xw = n & 7;   // read-side swizzle key (tok&7 == n&7)

    // per-wave stage of k-tile kt2 into buffer bufn: 8 K loads + 2 pos loads
    auto STAGE = [&](int kt2, int bufn) {
        const int kb = kt2 * KT3;
        __bf16* kd = &Ks[(size_t)bufn*8192];
        #pragma unroll
        for (int e = 0; e < 8; ++e) {
            int slot = w*512 + e*64 + lane;
            int tok = slot >> 5;
            int ch = ((slot & 31) ^ (tok & 7)) * 8;
            async_cp16(&ksrc0[(size_t)(kb + tok)*256 + ch], &kd[(size_t)slot*8]);
        }
        #pragma unroll
        for (int e = 0; e < 2; ++e) {
            int slot = w*128 + e*64 + lane;
            int row = slot >> 2;
            int ch = (slot & 3) * 8;
            async_cp16(&psrc0[(size_t)row*KSTR + kb + ch], &posb[(size_t)(bufn*256 + slot)*8]);
        }
    };

    STAGE(0, 0);
    int bc = 0, bn = 1;   // buffer of current tile / next tile
    for (int kt = 0; kt < NKT3; ++kt) {
        // issue next tile's loads (wraps to tile 0 on last iter; never consumed)
        STAGE(kt + 1 < NKT3 ? kt + 1 : 0, bn);
        asm volatile("s_waitcnt vmcnt(10)" ::: "memory");  // current tile landed; next stays in flight
        __builtin_amdgcn_s_barrier();
        asm volatile("" ::: "memory");

        const int kbase = kt * KT3;
        const __bf16* kb_ = &Ks[(size_t)bc*8192];
        const __bf16* pb_ = &posb[(size_t)bc*2048];

        // QK^T: D[q32][k32] per wave; each bk read feeds 2 MFMAs
        f32x4 sacc[2][2];
        #pragma unroll
        for (int f = 0; f < 2; ++f) {
            sacc[f][0] = (f32x4){0.f,0.f,0.f,0.f};
            sacc[f][1] = (f32x4){0.f,0.f,0.f,0.f};
        }
        #pragma unroll
        for (int c = 0; c < 8; ++c) {
            #pragma unroll
            for (int nt = 0; nt < 2; ++nt) {
                bf16x8 bk = *(const bf16x8*)&kb_[(size_t)((nt*16 + n)*32 + ((c*4 + quad) ^ xw))*8];
                sacc[0][nt] = __builtin_amdgcn_mfma_f32_16x16x32_bf16(aq[0][c], bk, sacc[0][nt], 0, 0, 0);
                sacc[1][nt] = __builtin_amdgcn_mfma_f32_16x16x32_bf16(aq[1][c], bk, sacc[1][nt], 0, 0, 0);
            }
        }

        // P = exp2(s); mask invalid tokens; write LDS (wave-local rows)
        #pragma unroll
        for (int f = 0; f < 2; ++f)
            #pragma unroll
            for (int nt = 0; nt < 2; ++nt) {
                const bool ok = (kbase + nt*16 + n) <= 4096;
                #pragma unroll
                for (int r = 0; r < 4; ++r) {
                    float pv = ok ? __builtin_amdgcn_exp2f(sacc[f][nt][r]) : 0.f;
                    Pb[(w*32 + f*16 + quad*4 + r)*40 + nt*16 + n] = (__bf16)pv;
                }
            }
        // Pb written+read by the same wave -> lgkmcnt dependency, no barrier

        // PV: D[q32][ch48]; each bp read feeds 2 MFMAs; l in ch 34 (ones row)
        {
            bf16x8 aP0 = *(const bf16x8*)&Pb[(w*32 + n)*40 + quad*8];
            bf16x8 aP1 = *(const bf16x8*)&Pb[(w*32 + 16 + n)*40 + quad*8];
            #pragma unroll
            for (int ct = 0; ct < 3; ++ct) {
                bf16x8 bp = *(const bf16x8*)&pb_[(size_t)((ct*16 + n)*4 + quad)*8];
                pacc[0][ct] = __builtin_amdgcn_mfma_f32_16x16x32_bf16(aP0, bp, pacc[0][ct], 0, 0, 0);
                pacc[1][ct] = __builtin_amdgcn_mfma_f32_16x16x32_bf16(aP1, bp, pacc[1][ct], 0, 0, 0);
            }
        }

        int b3 = 3 - bc - bn; bc = bn; bn = b3;   // rotate buffers
    }
    asm volatile("s_waitcnt vmcnt(0)" ::: "memory");   // drain wrap-stage before exit

    // epilogue: divide by l (ch 34 = ct 2, n 2), store out[b][34][4096]
    const int f32o = *flag;
    #pragma unroll
    for (int f = 0; f < 2; ++f) {
        float linv[4];
        #pragma unroll
        for (int r = 0; r < 4; ++r)
            linv[r] = 1.f / __shfl(pacc[f][2][r], (lane & 48) | 2, 64);
        #pragma unroll
        for (int ct = 0; ct < 3; ++ct) {
            int ch = ct*16 + n;
            if (ch >= 34) continue;
            #pragma unroll
            for (int r = 0; r < 4; ++r) {
                float v = pacc[f][ct][r] * linv[r];
                size_t oi = ((size_t)b*34 + ch)*HW + qt*64 + w*32 + f*16 + quad*4 + r;
                if (f32o) ((float*)outv)[oi] = v;
                else      ((bf16*)outv)[oi]  = __float2bfloat16(v);
            }
        }
    }
}

// ---------------------------------------------------------------------------
extern "C" void kernel_launch(void* const* d_in, const int* in_sizes, int n_in,
                              void* d_out, int out_size, void* d_ws, size_t ws_size,
                              hipStream_t stream)
{
    const void* x      = d_in[0];
    const void* y      = d_in[1];
    const void* feat1  = d_in[2];
    const void* feat2  = d_in[3];
    const void* pg_w1  = d_in[4];
    const void* pg_b1  = d_in[5];
    const void* pg_w2  = d_in[6];
    const void* pg_b2  = d_in[7];
    const void* fus_w1 = d_in[8];
    const void* fus_b1 = d_in[9];
    const void* fus_w2 = d_in[10];
    const void* fus_b2 = d_in[11];
    const void* dw_w   = d_in[12];
    const void* dw_b   = d_in[13];
    const void* pw_w   = d_in[14];
    const void* pw_b   = d_in[15];
    const void* dvec   = d_in[16];
    const void* dpos   = d_in[17];

    // ---- workspace layout (~64 MB) ----
    char* wsb = (char*)d_ws;
    int*  flag = (int*)wsb;
    size_t off = 16;
    bf16* R1   = (bf16*)(wsb + off); off += (size_t)NTOK*384*2;        // in_xy / yf / k_t
    bf16* bufH = (bf16*)(wsb + off); off += (size_t)NTOK*256*2;        // hx / h1 / hy / dwv
    bf16* q_t  = (bf16*)(wsb + off); off += (size_t)NTOK*256*2;
    bf16* pos  = (bf16*)(wsb + off); off += (size_t)NB*PROWS*KSTR*2;
    WsPtrs W;
    W.fw1t  = (bf16*)(wsb + off); off += 98304*2;
    W.fw2t  = (bf16*)(wsb + off); off += 65536*2;
    W.pwt   = (bf16*)(wsb + off); off += 65536*2;
    W.pgw1t = (bf16*)(wsb + off); off += 16384*2;
    W.pgw2t = (bf16*)(wsb + off); off += 4096*2;
    W.dwt   = (bf16*)(wsb + off); off += 2304*2;
    W.pos   = pos;
    W.posw  = (float*)(wsb + off); off += 256*4;
    W.fb1   = (float*)(wsb + off); off += 256*4;
    W.fb2   = (float*)(wsb + off); off += 256*4;
    W.pwb   = (float*)(wsb + off); off += 256*4;
    W.pgb1  = (float*)(wsb + off); off += 128*4;
    W.pgb2  = (float*)(wsb + off); off += 32*4;
    W.dwb   = (float*)(wsb + off); off += 256*4;

    bf16* in_xy = R1;
    bf16* yf    = R1;            // after in_xy dead
    bf16* k_t   = R1;            // after yf dead (row stride KSTR)

    dim3 b256(256);

    // 0. dtype detect + weight/pos prep
    detect_kernel<<<1, 256, 0, stream>>>((const ushort_t*)x, flag);
    prep_kernel<<<1024, b256, 0, stream>>>(fus_w1, fus_w2, pw_w, pg_w1, pg_w2, dw_w,
                                           fus_b1, fus_b2, pw_b, pg_b1, pg_b2, dw_b,
                                           dpos, W, flag);
    // 1. x-phase: transpose(x,feat1) -> in_xy; F1x -> bufH; F2x -> q_t (scaled)
    transpose_kernel<<<dim3(64,6,NB), b256, 0, stream>>>(x, feat1, in_xy, flag);
    gemm_mfma<8, true, false, 0><<<dim3(256,2), b256, 0, stream>>>(
        in_xy, 384, W.fw1t, 384, W.fb1, nullptr, bufH, 256, 384, 1.f);
    gemm_mfma<8, false, false, 0><<<dim3(256,2), b256, 0, stream>>>(
        bufH, 256, W.fw2t, 256, W.fb2, nullptr, q_t, 256, 256, QSCALE);
    // 2. y-phase: transpose(y,feat2) -> in_xy
    transpose_kernel<<<dim3(64,6,NB), b256, 0, stream>>>(y, feat2, in_xy, flag);
    // 3. posgen: L1 (feat2 cols, meshgrid epilogue) -> bufH; L2 -> pos rows 0..31
    gemm_mfma<8, true, true, 0><<<dim3(256,1), b256, 0, stream>>>(
        in_xy + 256, 384, W.pgw1t, 128, W.pgb1, W.posw, bufH, 128, 128, 1.f);
    gemm_mfma<2, true, false, 1><<<dim3(256,1), b256, 0, stream>>>(
        bufH, 128, W.pgw2t, 128, W.pgb2, nullptr, pos, 0, 128, 1.f);
    // 4. fuser-y: L1 -> bufH; L2 -> yf (R1)
    gemm_mfma<8, true, false, 0><<<dim3(256,2), b256, 0, stream>>>(
        in_xy, 384, W.fw1t, 384, W.fb1, nullptr, bufH, 256, 384, 1.f);
    gemm_mfma<8, false, false, 0><<<dim3(256,2), b256, 0, stream>>>(
        bufH, 256, W.fw2t, 256, W.fb2, nullptr, yf, 256, 256, 1.f);
    // 5. depthwise: yf -> bufH (dwv)
    dw_kernel<<<dim3(4096), b256, 0, stream>>>(yf, W.dwt, W.dwb, bufH);
    // 6. k dustbin, then pointwise: bufH -> k_t (KSTR rows)
    fill_late_kernel<<<dim3(NB), b256, 0, stream>>>(dvec, k_t, flag);
    gemm_mfma<8, false, false, 2><<<dim3(256,2), b256, 0, stream>>>(
        bufH, 256, W.pwt, 256, W.pwb, nullptr, k_t, 256, 256, 1.f);
    // 7. attention
    attn_kernel<<<dim3(512), dim3(128), 0, stream>>>(q_t, k_t, pos, d_out, flag);
}

// Round 5
// 499.030 us; speedup vs baseline: 1.0887x; 1.0887x over previous
//
#include <hip/hip_runtime.h>
#include <hip/hip_bf16.h>

typedef __hip_bfloat16 bf16;
typedef unsigned short ushort_t;
typedef __bf16 bf16x8 __attribute__((ext_vector_type(8)));
typedef float  f32x4  __attribute__((ext_vector_type(4)));

#define HW    4096
#define NB    8
#define KSTR  4160     // padded token count for k/pos; token 4096 = dustbin
#define NTOK  32768    // NB*HW
#define PROWS 64       // padded pos channel rows (34 real + ones@34 + zeros, 48..63 slack)
#define QSCALE 0.0901684400557f   // (1/16) * log2(e): folds exp->exp2

__device__ __forceinline__ float lde(const void* p, size_t i, int f32f) {
    return f32f ? ((const float*)p)[i] : (float)((const bf16*)p)[i];
}
__device__ __forceinline__ ushort_t f2bu(float f){ union { __bf16 b; ushort_t u; } cv; cv.b = (__bf16)f; return cv.u; }

__device__ __forceinline__ void async_cp16(const void* g, void* l) {
    __builtin_amdgcn_global_load_lds(
        (const __attribute__((address_space(1))) unsigned int*)g,
        (__attribute__((address_space(3))) unsigned int*)l, 16, 0, 0);
}

// ---------------------------------------------------------------------------
// dtype detector: flag=1 if inputs are float32, 0 if bf16.
// ---------------------------------------------------------------------------
__global__ void detect_kernel(const ushort_t* xb, int* flag)
{
    __shared__ int cnt;
    const int t = threadIdx.x;
    if (t == 0) cnt = 0;
    __syncthreads();
    ushort_t h = xb[2*t];
    int e = (h >> 7) & 0xFF;
    if (e >= 133) atomicAdd(&cnt, 1);
    __syncthreads();
    if (t == 0) *flag = (cnt > 8) ? 1 : 0;
}

// ---------------------------------------------------------------------------
// prep: weights/biases -> bf16/f32 ws copies; dw taps transposed; pos fixed
// rows (mesh 32/33, ones 34, zeros 35..47, dustbin col 4096, ztail 4097+).
// ---------------------------------------------------------------------------
struct WsPtrs {
    bf16 *fw1t, *fw2t, *pwt, *pgw1t, *pgw2t, *dwt, *pos;
    float *posw, *fb1, *fb2, *pwb, *pgb1, *pgb2, *dwb;
};

__global__ __launch_bounds__(256) void prep_kernel(
    const void* fus_w1, const void* fus_w2, const void* pw_w,
    const void* pg_w1, const void* pg_w2, const void* dw_w,
    const void* fus_b1, const void* fus_b2, const void* pw_b,
    const void* pg_b1, const void* pg_b2, const void* dw_b,
    const void* dpos, WsPtrs W, const int* flag)
{
    const int f = *flag;
    const long n_w1 = 98304, n_w2 = 65536, n_pw = 65536, n_g1 = 16384, n_g2 = 4096;
    const long n_posw = 256, n_dwt = 2304;
    const long n_b = 256, n_gb1 = 128, n_gb2 = 32;
    const long n_mesh = 65536;            // rows 32/33, tok 0..4095
    const long n_pad  = 8L*14*KSTR;       // rows 34..47 (34=ones) all cols
    const long n_dust = 272;              // rows 0..33 col 4096
    const long n_zt   = 8L*34*63;         // rows 0..33 cols 4097..4159
    const long total = n_w1+n_w2+n_pw+n_g1+n_g2+n_posw+n_dwt
                     + 3*n_b + n_gb1 + n_gb2 + n_b + n_mesh + n_pad + n_dust + n_zt;

    for (long i = blockIdx.x*256L + threadIdx.x; i < total; i += gridDim.x*256L) {
        long j = i;
        if (j < n_w1) { W.fw1t[j] = __float2bfloat16(lde(fus_w1, j, f)); continue; } j -= n_w1;
        if (j < n_w2) { W.fw2t[j] = __float2bfloat16(lde(fus_w2, j, f)); continue; } j -= n_w2;
        if (j < n_pw) { W.pwt[j]  = __float2bfloat16(lde(pw_w,  j, f)); continue; } j -= n_pw;
        if (j < n_g1) { W.pgw1t[j] = __float2bfloat16(lde(pg_w1, (j>>7)*130 + 2 + (j&127), f)); continue; } j -= n_g1;
        if (j < n_g2) { W.pgw2t[j] = __float2bfloat16(lde(pg_w2, j, f)); continue; } j -= n_g2;
        if (j < n_posw) { W.posw[j] = lde(pg_w1, (j>>1)*130 + (j&1), f); continue; } j -= n_posw;
        if (j < n_dwt) { W.dwt[j] = __float2bfloat16(lde(dw_w, (j&255)*9 + (j>>8), f)); continue; } j -= n_dwt;
        if (j < n_b)   { W.fb1[j] = lde(fus_b1, j, f); continue; } j -= n_b;
        if (j < n_b)   { W.fb2[j] = lde(fus_b2, j, f); continue; } j -= n_b;
        if (j < n_b)   { W.pwb[j] = lde(pw_b, j, f); continue; } j -= n_b;
        if (j < n_gb1) { W.pgb1[j] = lde(pg_b1, j, f); continue; } j -= n_gb1;
        if (j < n_gb2) { W.pgb2[j] = lde(pg_b2, j, f); continue; } j -= n_gb2;
        if (j < n_b)   { W.dwb[j] = lde(dw_b, j, f); continue; } j -= n_b;
        if (j < n_mesh) {
            long b = j >> 13; int rr = (int)((j>>12)&1); int tok = (int)(j & 4095);
            float v = rr ? (-1.f + 2.f*(float)((tok>>6)&63)/63.f)
                         : (-1.f + 2.f*(float)(tok&63)/63.f);
            W.pos[((size_t)b*PROWS + 32 + rr)*KSTR + tok] = __float2bfloat16(v);
            continue;
        } j -= n_mesh;
        if (j < n_pad) {
            long b = j / (14L*KSTR); long rem = j % (14L*KSTR);
            int row = 34 + (int)(rem / KSTR); int tok = (int)(rem % KSTR);
            W.pos[((size_t)b*PROWS + row)*KSTR + tok] = __float2bfloat16(row == 34 ? 1.f : 0.f);
            continue;
        } j -= n_pad;
        if (j < n_dust) {
            long b = j / 34; int ch = (int)(j % 34);
            W.pos[((size_t)b*PROWS + ch)*KSTR + 4096] = __float2bfloat16(lde(dpos, ch, f));
            continue;
        } j -= n_dust;
        { long b = j / (34*63); long rem = j % (34*63);
          int ch = (int)(rem / 63); int cc = (int)(rem % 63);
          W.pos[((size_t)b*PROWS + ch)*KSTR + 4097 + cc] = __float2bfloat16(0.f); }
    }
}

// ---------------------------------------------------------------------------
// transpose: ch-major [b][C][4096] (ext dtype) -> token-major bf16 rows of
// in_xy [32768][384] (main -> cols 0..255, feat -> cols 256..383).
// ---------------------------------------------------------------------------
__global__ __launch_bounds__(256) void transpose_kernel(
    const void* main_src, const void* feat_src, bf16* __restrict__ dst, const int* flag)
{
    __shared__ float Tt[64*65];
    const int t = threadIdx.x;
    const int p0 = blockIdx.x * 64;
    const int cht = blockIdx.y;
    const int b = blockIdx.z;
    const int f = *flag;

    const void* src; int ch0, srcC, dc0;
    if (cht < 4) { src = main_src; ch0 = cht*64; srcC = 256; dc0 = ch0; }
    else         { src = feat_src; ch0 = (cht-4)*64; srcC = 128; dc0 = 256 + (cht-4)*64; }

    const int p = t & 63, cq = t >> 6;
    #pragma unroll
    for (int e = 0; e < 16; ++e) {
        int c = e*4 + cq;
        Tt[p*65 + c] = lde(src, ((size_t)b*srcC + ch0 + c)*HW + p0 + p, f);
    }
    __syncthreads();
    const int pr = t >> 2, cs = (t & 3) * 16;
    union { uint4 u4[2]; ushort_t us[16]; } pk;
    #pragma unroll
    for (int u = 0; u < 16; ++u) pk.us[u] = f2bu(Tt[pr*65 + cs + u]);
    ushort_t* op = (ushort_t*)dst + ((size_t)b*HW + p0 + pr)*384 + dc0 + cs;
    *(uint4*)op = pk.u4[0];
    *((uint4*)op + 1) = pk.u4[1];
}

// ---------------------------------------------------------------------------
// MFMA GEMM, token-major. A [NTOK][sa] bf16 (k-contig), Bw [M][ldb] bf16.
// OMODE 0: out[tok*sm + m]; 2: out[(tok + 64*(tok>>12))*sm + m] (k_t);
// 1: pos-mode out[((tok>>12)*PROWS + m)*KSTR + tok&4095].
// ---------------------------------------------------------------------------
template<int MT, bool RELU, bool POSEPI, int OMODE>
__global__ __launch_bounds__(256) void gemm_mfma(
    const bf16* __restrict__ A, int sa,
    const bf16* __restrict__ Bw, int ldb,
    const float* __restrict__ bias, const float* __restrict__ posw,
    bf16* __restrict__ out, int sm, int K, float oscale)
{
    const int t = threadIdx.x;
    const int w = t >> 6, lane = t & 63;
    const int n = lane & 15, quad = lane >> 4;
    const int p0 = blockIdx.x * 128;
    const int m0 = blockIdx.y * (MT*16);
    const int rowbase = p0 + w*32;

    f32x4 acc[2][MT];
    #pragma unroll
    for (int pt = 0; pt < 2; ++pt)
        #pragma unroll
        for (int mt = 0; mt < MT; ++mt) acc[pt][mt] = (f32x4){0.f,0.f,0.f,0.f};

    for (int k0 = 0; k0 < K; k0 += 32) {
        bf16x8 ap[2];
        #pragma unroll
        for (int pt = 0; pt < 2; ++pt)
            ap[pt] = *(const bf16x8*)&A[(size_t)(rowbase + pt*16 + n)*sa + k0 + quad*8];
        #pragma unroll
        for (int mt = 0; mt < MT; ++mt) {
            bf16x8 bw = *(const bf16x8*)&Bw[(size_t)(m0 + mt*16 + n)*ldb + k0 + quad*8];
            acc[0][mt] = __builtin_amdgcn_mfma_f32_16x16x32_bf16(ap[0], bw, acc[0][mt], 0, 0, 0);
            acc[1][mt] = __builtin_amdgcn_mfma_f32_16x16x32_bf16(ap[1], bw, acc[1][mt], 0, 0, 0);
        }
    }

    #pragma unroll
    for (int mt = 0; mt < MT; ++mt) {
        const int m = m0 + mt*16 + n;
        const float bi = bias[m];
        float w0 = 0.f, w1 = 0.f;
        if (POSEPI) { w0 = posw[m*2]; w1 = posw[m*2 + 1]; }
        #pragma unroll
        for (int pt = 0; pt < 2; ++pt) {
            const int tokb = rowbase + pt*16 + quad*4;
            if (OMODE == 1) {
                union { uint2 u2; ushort_t us[4]; } pk;
                #pragma unroll
                for (int r = 0; r < 4; ++r) {
                    float v = acc[pt][mt][r] + bi;
                    if (RELU) v = fmaxf(v, 0.f);
                    pk.us[r] = f2bu(v * oscale);
                }
                size_t oi = ((size_t)(tokb >> 12)*PROWS + m)*KSTR + (tokb & 4095);
                *(uint2*)((ushort_t*)out + oi) = pk.u2;
            } else {
                #pragma unroll
                for (int r = 0; r < 4; ++r) {
                    int tok = tokb + r;
                    float v = acc[pt][mt][r] + bi;
                    if (POSEPI) {
                        float gx1 = 2.f * (float)(tok & 63) / 63.f;
                        float gy1 = 2.f * (float)((tok >> 6) & 63) / 63.f;
                        v += w0*gx1 + w1*gy1;
                    }
                    if (RELU) v = fmaxf(v, 0.f);
                    v *= oscale;
                    size_t row = (OMODE == 2) ? (size_t)tok + 64*(size_t)(tok >> 12) : (size_t)tok;
                    out[row*sm + m] = __float2bfloat16(v);
                }
            }
        }
    }
}

// ---------------------------------------------------------------------------
// depthwise 3x3 SAME + bias, token-major bf16.
// ---------------------------------------------------------------------------
__global__ __launch_bounds__(256) void dw_kernel(
    const bf16* __restrict__ in, const bf16* __restrict__ dwt,
    const float* __restrict__ dwb, bf16* __restrict__ out)
{
    const int t = threadIdx.x;
    const int tok = blockIdx.x*8 + (t >> 5);
    const int c8 = (t & 31) * 8;
    const int b = tok >> 12, p = tok & 4095;
    const int i = p >> 6, j = p & 63;

    float acc[8];
    #pragma unroll
    for (int u = 0; u < 8; ++u) acc[u] = dwb[c8 + u];

    #pragma unroll
    for (int di = 0; di < 3; ++di) {
        int ii = i + di - 1;
        if (ii < 0 || ii >= 64) continue;
        #pragma unroll
        for (int dj = 0; dj < 3; ++dj) {
            int jj = j + dj - 1;
            if (jj < 0 || jj >= 64) continue;
            int tok2 = (b << 12) + ii*64 + jj;
            bf16x8 xv = *(const bf16x8*)&in[(size_t)tok2*256 + c8];
            bf16x8 wv = *(const bf16x8*)&dwt[(di*3 + dj)*256 + c8];
            #pragma unroll
            for (int u = 0; u < 8; ++u) acc[u] += (float)xv[u] * (float)wv[u];
        }
    }
    union { uint4 u4; ushort_t us[8]; } pk;
    #pragma unroll
    for (int u = 0; u < 8; ++u) pk.us[u] = f2bu(acc[u]);
    *(uint4*)((ushort_t*)out + (size_t)tok*256 + c8) = pk.u4;
}

// ---------------------------------------------------------------------------
// fill_late: k dustbin token row.
// ---------------------------------------------------------------------------
__global__ __launch_bounds__(256) void fill_late_kernel(
    const void* dvec, bf16* __restrict__ k_t, const int* flag)
{
    const int b = blockIdx.x, t = threadIdx.x;
    k_t[((size_t)b*KSTR + 4096)*256 + t] = __float2bfloat16(lde(dvec, t, *flag));
}

// ---------------------------------------------------------------------------
// MFMA flash attention v6: LDS-op-minimized, occupancy-preserving.
// Round-4 lesson: v3/v4 were LDS-instruction-throughput-bound (~79% LDS busy);
// v5 halved LDS ops but dropped to 1 wave/SIMD and regressed (latency-exposed).
// v6: ONE 512-thread block per CU (grid 256 = 32 blocks/XCD, batch-pinned),
// 8 waves = 2/SIMD, 128 q-rows/block, 64-token k-tiles, double-buffered K/pos.
//   QK^T k-split: waves = 2 q-groups x 4 k-slices. Each wave holds 4 Q-frags
//   (64 q-rows, 128 VGPR) in registers and reads only its 16-token k-slice:
//   8 ds_read_b128 feed 32 MFMAs (4 MFMA/read).
//   P crosses waves via LDS Pb (per q-group) with a second raw barrier
//   (lgkmcnt-only -- vmcnt stays in flight for the next tile's stage).
//   PV q-split: each wave 16 q-rows over the full 64k: 8 reads, 6 MFMAs.
// Per CU-tile: 128 b128 + 128 b16 (vs v3's 320+128) -- balanced vs MFMA pipe.
// No-max softmax via exp2 (log2e pre-folded into q); l via ones-row (ch 34).
// ---------------------------------------------------------------------------
__global__ __launch_bounds__(512, 2) void attn_kernel(
    const bf16* __restrict__ q_t, const bf16* __restrict__ k_t,
    const bf16* __restrict__ pos, void* outv, const int* flag)
{
    __shared__ __align__(16) __bf16 Ks[2*2048*8];   // 2 bufs x (64 tok x 32 chunks x 16B), swizzled
    __shared__ __align__(16) __bf16 posb[2*512*8];  // 2 bufs x (64 rows x 8 chunks x 16B), swizzled
    __shared__ __align__(16) __bf16 Pb[2*64*72];    // per-qgroup P [64 q][64 k], stride 72

    const int t = threadIdx.x;
    const int w = t >> 6, lane = t & 63;            // 8 waves
    const int n = lane & 15, quad = lane >> 4;
    const int qg = w >> 2, ks = w & 3;              // q-group (2) x k-slice (4)
    const int bid = blockIdx.x;
    const int b = bid & 7;          // batch == XCD id (round-robin dispatch)
    const int qt = bid >> 3;        // 0..31, 128 q-rows per block

    // Q fragments: the whole q-group (64 rows = 4 frags) per wave, in registers
    bf16x8 aq[4][8];
    #pragma unroll
    for (int f = 0; f < 4; ++f) {
        size_t qrow = (size_t)b*HW + qt*128 + qg*64 + f*16 + n;
        #pragma unroll
        for (int c = 0; c < 8; ++c)
            aq[f][c] = *(const bf16x8*)&q_t[qrow*256 + c*32 + quad*8];
    }

    f32x4 pacc[3];
    #pragma unroll
    for (int ct = 0; ct < 3; ++ct) pacc[ct] = (f32x4){0.f,0.f,0.f,0.f};

    const ushort_t* ksrc0 = (const ushort_t*)k_t + (size_t)b*KSTR*256;
    const ushort_t* psrc0 = (const ushort_t*)pos + (size_t)b*PROWS*KSTR;
    const int xw = n & 7;   // read-side swizzle key (tok&7 == n&7, row&7 == n&7)

    // per-wave stage of 64-token k-tile kt2 into buffer bufn: 4 K + 1 pos load
    auto STAGE = [&](int kt2, int bufn) {
        const int kb = kt2 * 64;
        __bf16* kd = &Ks[(size_t)bufn*16384];
        #pragma unroll
        for (int e = 0; e < 4; ++e) {
            int slot = w*256 + e*64 + lane;          // 0..2047
            int tok = slot >> 5;
            int ch = ((slot & 31) ^ (tok & 7)) * 8;
            async_cp16(&ksrc0[(size_t)(kb + tok)*256 + ch], &kd[(size_t)slot*8]);
        }
        {
            int slot = w*64 + lane;                  // 0..511
            int row = slot >> 3;
            int ch = ((slot & 7) ^ (row & 7)) * 8;
            async_cp16(&psrc0[(size_t)row*KSTR + kb + ch], &posb[(size_t)(bufn*512 + slot)*8]);
        }
    };

    STAGE(0, 0);
    for (int kt = 0; kt < 65; ++kt) {
        const int cur = kt & 1;
        // barrier1: STAGE(kt) landed in buf[cur]; all PV reads of buf[cur^1] done
        asm volatile("s_waitcnt vmcnt(0)" ::: "memory");
        __builtin_amdgcn_s_barrier();
        asm volatile("" ::: "memory");
        if (kt + 1 < 65) STAGE(kt + 1, cur ^ 1);   // flies under the whole body

        const __bf16* kb_ = &Ks[(size_t)cur*16384];
        const __bf16* pb_ = &posb[(size_t)cur*4096];
        __bf16* Pq = &Pb[(size_t)qg*(64*72)];

        // QK^T: 64 q-rows x this wave's 16-token k-slice; 8 reads, 32 MFMAs
        f32x4 sacc[4];
        #pragma unroll
        for (int f = 0; f < 4; ++f) sacc[f] = (f32x4){0.f,0.f,0.f,0.f};
        #pragma unroll
        for (int c = 0; c < 8; ++c) {
            bf16x8 bk = *(const bf16x8*)&kb_[(size_t)((ks*16 + n)*32 + ((c*4 + quad) ^ xw))*8];
            #pragma unroll
            for (int f = 0; f < 4; ++f)
                sacc[f] = __builtin_amdgcn_mfma_f32_16x16x32_bf16(aq[f][c], bk, sacc[f], 0, 0, 0);
        }

        // P = exp2(s); mask invalid tokens; write own k-slice columns of Pq
        const bool ok = (kt*64 + ks*16 + n) <= 4096;
        #pragma unroll
        for (int f = 0; f < 4; ++f)
            #pragma unroll
            for (int r = 0; r < 4; ++r) {
                float pv = ok ? __builtin_amdgcn_exp2f(sacc[f][r]) : 0.f;
                Pq[(f*16 + quad*4 + r)*72 + ks*16 + n] = (__bf16)pv;
            }

        // barrier2: Pb complete (lgkmcnt only -- staged loads stay in flight)
        asm volatile("s_waitcnt lgkmcnt(0)" ::: "memory");
        __builtin_amdgcn_s_barrier();
        asm volatile("" ::: "memory");

        // PV: this wave's 16 q-rows over all 64 k; l accumulates via ones row
        #pragma unroll
        for (int c = 0; c < 2; ++c) {
            bf16x8 aP = *(const bf16x8*)&Pq[(size_t)((ks*16 + n)*72 + c*32 + quad*8)];
            #pragma unroll
            for (int ct = 0; ct < 3; ++ct) {
                bf16x8 bp = *(const bf16x8*)&pb_[(size_t)((ct*16 + n)*8 + ((c*4 + quad) ^ xw))*8];
                pacc[ct] = __builtin_amdgcn_mfma_f32_16x16x32_bf16(aP, bp, pacc[ct], 0, 0, 0);
            }
        }
    }
    asm volatile("s_waitcnt vmcnt(0)" ::: "memory");

    // epilogue: divide by l (ch 34 = ct 2, n 2), store out[b][34][4096]
    const int f32o = *flag;
    float linv[4];
    #pragma unroll
    for (int r = 0; r < 4; ++r)
        linv[r] = 1.f / __shfl(pacc[2][r], (lane & 48) | 2, 64);
    #pragma unroll
    for (int ct = 0; ct < 3; ++ct) {
        int ch = ct*16 + n;
        if (ch >= 34) continue;
        #pragma unroll
        for (int r = 0; r < 4; ++r) {
            float v = pacc[ct][r] * linv[r];
            size_t oi = ((size_t)b*34 + ch)*HW + qt*128 + qg*64 + ks*16 + quad*4 + r;
            if (f32o) ((float*)outv)[oi] = v;
            else      ((bf16*)outv)[oi]  = __float2bfloat16(v);
        }
    }
}

// ---------------------------------------------------------------------------
extern "C" void kernel_launch(void* const* d_in, const int* in_sizes, int n_in,
                              void* d_out, int out_size, void* d_ws, size_t ws_size,
                              hipStream_t stream)
{
    const void* x      = d_in[0];
    const void* y      = d_in[1];
    const void* feat1  = d_in[2];
    const void* feat2  = d_in[3];
    const void* pg_w1  = d_in[4];
    const void* pg_b1  = d_in[5];
    const void* pg_w2  = d_in[6];
    const void* pg_b2  = d_in[7];
    const void* fus_w1 = d_in[8];
    const void* fus_b1 = d_in[9];
    const void* fus_w2 = d_in[10];
    const void* fus_b2 = d_in[11];
    const void* dw_w   = d_in[12];
    const void* dw_b   = d_in[13];
    const void* pw_w   = d_in[14];
    const void* pw_b   = d_in[15];
    const void* dvec   = d_in[16];
    const void* dpos   = d_in[17];

    // ---- workspace layout (~64 MB) ----
    char* wsb = (char*)d_ws;
    int*  flag = (int*)wsb;
    size_t off = 16;
    bf16* R1   = (bf16*)(wsb + off); off += (size_t)NTOK*384*2;        // in_xy / yf / k_t
    bf16* bufH = (bf16*)(wsb + off); off += (size_t)NTOK*256*2;        // hx / h1 / hy / dwv
    bf16* q_t  = (bf16*)(wsb + off); off += (size_t)NTOK*256*2;
    bf16* pos  = (bf16*)(wsb + off); off += (size_t)NB*PROWS*KSTR*2;
    WsPtrs W;
    W.fw1t  = (bf16*)(wsb + off); off += 98304*2;
    W.fw2t  = (bf16*)(wsb + off); off += 65536*2;
    W.pwt   = (bf16*)(wsb + off); off += 65536*2;
    W.pgw1t = (bf16*)(wsb + off); off += 16384*2;
    W.pgw2t = (bf16*)(wsb + off); off += 4096*2;
    W.dwt   = (bf16*)(wsb + off); off += 2304*2;
    W.pos   = pos;
    W.posw  = (float*)(wsb + off); off += 256*4;
    W.fb1   = (float*)(wsb + off); off += 256*4;
    W.fb2   = (float*)(wsb + off); off += 256*4;
    W.pwb   = (float*)(wsb + off); off += 256*4;
    W.pgb1  = (float*)(wsb + off); off += 128*4;
    W.pgb2  = (float*)(wsb + off); off += 32*4;
    W.dwb   = (float*)(wsb + off); off += 256*4;

    bf16* in_xy = R1;
    bf16* yf    = R1;            // after in_xy dead
    bf16* k_t   = R1;            // after yf dead (row stride KSTR)

    dim3 b256(256);

    // 0. dtype detect + weight/pos prep
    detect_kernel<<<1, 256, 0, stream>>>((const ushort_t*)x, flag);
    prep_kernel<<<1024, b256, 0, stream>>>(fus_w1, fus_w2, pw_w, pg_w1, pg_w2, dw_w,
                                           fus_b1, fus_b2, pw_b, pg_b1, pg_b2, dw_b,
                                           dpos, W, flag);
    // 1. x-phase: transpose(x,feat1) -> in_xy; F1x -> bufH; F2x -> q_t (scaled)
    transpose_kernel<<<dim3(64,6,NB), b256, 0, stream>>>(x, feat1, in_xy, flag);
    gemm_mfma<8, true, false, 0><<<dim3(256,2), b256, 0, stream>>>(
        in_xy, 384, W.fw1t, 384, W.fb1, nullptr, bufH, 256, 384, 1.f);
    gemm_mfma<8, false, false, 0><<<dim3(256,2), b256, 0, stream>>>(
        bufH, 256, W.fw2t, 256, W.fb2, nullptr, q_t, 256, 256, QSCALE);
    // 2. y-phase: transpose(y,feat2) -> in_xy
    transpose_kernel<<<dim3(64,6,NB), b256, 0, stream>>>(y, feat2, in_xy, flag);
    // 3. posgen: L1 (feat2 cols, meshgrid epilogue) -> bufH; L2 -> pos rows 0..31
    gemm_mfma<8, true, true, 0><<<dim3(256,1), b256, 0, stream>>>(
        in_xy + 256, 384, W.pgw1t, 128, W.pgb1, W.posw, bufH, 128, 128, 1.f);
    gemm_mfma<2, true, false, 1><<<dim3(256,1), b256, 0, stream>>>(
        bufH, 128, W.pgw2t, 128, W.pgb2, nullptr, pos, 0, 128, 1.f);
    // 4. fuser-y: L1 -> bufH; L2 -> yf (R1)
    gemm_mfma<8, true, false, 0><<<dim3(256,2), b256, 0, stream>>>(
        in_xy, 384, W.fw1t, 384, W.fb1, nullptr, bufH, 256, 384, 1.f);
    gemm_mfma<8, false, false, 0><<<dim3(256,2), b256, 0, stream>>>(
        bufH, 256, W.fw2t, 256, W.fb2, nullptr, yf, 256, 256, 1.f);
    // 5. depthwise: yf -> bufH (dwv)
    dw_kernel<<<dim3(4096), b256, 0, stream>>>(yf, W.dwt, W.dwb, bufH);
    // 6. k dustbin, then pointwise: bufH -> k_t (KSTR rows)
    fill_late_kernel<<<dim3(NB), b256, 0, stream>>>(dvec, k_t, flag);
    gemm_mfma<8, false, false, 2><<<dim3(256,2), b256, 0, stream>>>(
        bufH, 256, W.pwt, 256, W.pwb, nullptr, k_t, 256, 256, 1.f);
    // 7. attention
    attn_kernel<<<dim3(256), dim3(512), 0, stream>>>(q_t, k_t, pos, d_out, flag);
}

// Round 13
// 480.244 us; speedup vs baseline: 1.1313x; 1.0391x over previous
//
#include <hip/hip_runtime.h>
#include <hip/hip_bf16.h>

typedef __hip_bfloat16 bf16;
typedef unsigned short ushort_t;
typedef __bf16 bf16x8 __attribute__((ext_vector_type(8)));
typedef float  f32x4  __attribute__((ext_vector_type(4)));

#define HW    4096
#define NB    8
#define KSTR  4160     // padded token count for k/pos; token 4096 = dustbin
#define NTOK  32768    // NB*HW
#define PROWS 64       // padded pos channel rows (34 real + ones@34 + zeros, 48..63 slack)
#define QSCALE 0.0901684400557f   // (1/16) * log2(e): folds exp->exp2

__device__ __forceinline__ float lde(const void* p, size_t i, int f32f) {
    return f32f ? ((const float*)p)[i] : (float)((const bf16*)p)[i];
}
__device__ __forceinline__ ushort_t f2bu(float f){ union { __bf16 b; ushort_t u; } cv; cv.b = (__bf16)f; return cv.u; }

__device__ __forceinline__ void async_cp16(const void* g, void* l) {
    __builtin_amdgcn_global_load_lds(
        (const __attribute__((address_space(1))) unsigned int*)g,
        (__attribute__((address_space(3))) unsigned int*)l, 16, 0, 0);
}

// ---------------------------------------------------------------------------
// dtype detector: flag=1 if inputs are float32, 0 if bf16.
// ---------------------------------------------------------------------------
__global__ void detect_kernel(const ushort_t* xb, int* flag)
{
    __shared__ int cnt;
    const int t = threadIdx.x;
    if (t == 0) cnt = 0;
    __syncthreads();
    ushort_t h = xb[2*t];
    int e = (h >> 7) & 0xFF;
    if (e >= 133) atomicAdd(&cnt, 1);
    __syncthreads();
    if (t == 0) *flag = (cnt > 8) ? 1 : 0;
}

// ---------------------------------------------------------------------------
// prep: weights/biases -> bf16/f32 ws copies; dw taps transposed; pos fixed
// rows (mesh 32/33, ones 34, zeros 35..47, dustbin col 4096, ztail 4097+).
// ---------------------------------------------------------------------------
struct WsPtrs {
    bf16 *fw1t, *fw2t, *pwt, *pgw1t, *pgw2t, *dwt, *pos;
    float *posw, *fb1, *fb2, *pwb, *pgb1, *pgb2, *dwb;
};

__global__ __launch_bounds__(256) void prep_kernel(
    const void* fus_w1, const void* fus_w2, const void* pw_w,
    const void* pg_w1, const void* pg_w2, const void* dw_w,
    const void* fus_b1, const void* fus_b2, const void* pw_b,
    const void* pg_b1, const void* pg_b2, const void* dw_b,
    const void* dpos, WsPtrs W, const int* flag)
{
    const int f = *flag;
    const long n_w1 = 98304, n_w2 = 65536, n_pw = 65536, n_g1 = 16384, n_g2 = 4096;
    const long n_posw = 256, n_dwt = 2304;
    const long n_b = 256, n_gb1 = 128, n_gb2 = 32;
    const long n_mesh = 65536;            // rows 32/33, tok 0..4095
    const long n_pad  = 8L*14*KSTR;       // rows 34..47 (34=ones) all cols
    const long n_dust = 272;              // rows 0..33 col 4096
    const long n_zt   = 8L*34*63;         // rows 0..33 cols 4097..4159
    const long total = n_w1+n_w2+n_pw+n_g1+n_g2+n_posw+n_dwt
                     + 3*n_b + n_gb1 + n_gb2 + n_b + n_mesh + n_pad + n_dust + n_zt;

    for (long i = blockIdx.x*256L + threadIdx.x; i < total; i += gridDim.x*256L) {
        long j = i;
        if (j < n_w1) { W.fw1t[j] = __float2bfloat16(lde(fus_w1, j, f)); continue; } j -= n_w1;
        if (j < n_w2) { W.fw2t[j] = __float2bfloat16(lde(fus_w2, j, f)); continue; } j -= n_w2;
        if (j < n_pw) { W.pwt[j]  = __float2bfloat16(lde(pw_w,  j, f)); continue; } j -= n_pw;
        if (j < n_g1) { W.pgw1t[j] = __float2bfloat16(lde(pg_w1, (j>>7)*130 + 2 + (j&127), f)); continue; } j -= n_g1;
        if (j < n_g2) { W.pgw2t[j] = __float2bfloat16(lde(pg_w2, j, f)); continue; } j -= n_g2;
        if (j < n_posw) { W.posw[j] = lde(pg_w1, (j>>1)*130 + (j&1), f); continue; } j -= n_posw;
        if (j < n_dwt) { W.dwt[j] = __float2bfloat16(lde(dw_w, (j&255)*9 + (j>>8), f)); continue; } j -= n_dwt;
        if (j < n_b)   { W.fb1[j] = lde(fus_b1, j, f); continue; } j -= n_b;
        if (j < n_b)   { W.fb2[j] = lde(fus_b2, j, f); continue; } j -= n_b;
        if (j < n_b)   { W.pwb[j] = lde(pw_b, j, f); continue; } j -= n_b;
        if (j < n_gb1) { W.pgb1[j] = lde(pg_b1, j, f); continue; } j -= n_gb1;
        if (j < n_gb2) { W.pgb2[j] = lde(pg_b2, j, f); continue; } j -= n_gb2;
        if (j < n_b)   { W.dwb[j] = lde(dw_b, j, f); continue; } j -= n_b;
        if (j < n_mesh) {
            long b = j >> 13; int rr = (int)((j>>12)&1); int tok = (int)(j & 4095);
            float v = rr ? (-1.f + 2.f*(float)((tok>>6)&63)/63.f)
                         : (-1.f + 2.f*(float)(tok&63)/63.f);
            W.pos[((size_t)b*PROWS + 32 + rr)*KSTR + tok] = __float2bfloat16(v);
            continue;
        } j -= n_mesh;
        if (j < n_pad) {
            long b = j / (14L*KSTR); long rem = j % (14L*KSTR);
            int row = 34 + (int)(rem / KSTR); int tok = (int)(rem % KSTR);
            W.pos[((size_t)b*PROWS + row)*KSTR + tok] = __float2bfloat16(row == 34 ? 1.f : 0.f);
            continue;
        } j -= n_pad;
        if (j < n_dust) {
            long b = j / 34; int ch = (int)(j % 34);
            W.pos[((size_t)b*PROWS + ch)*KSTR + 4096] = __float2bfloat16(lde(dpos, ch, f));
            continue;
        } j -= n_dust;
        { long b = j / (34*63); long rem = j % (34*63);
          int ch = (int)(rem / 63); int cc = (int)(rem % 63);
          W.pos[((size_t)b*PROWS + ch)*KSTR + 4097 + cc] = __float2bfloat16(0.f); }
    }
}

// ---------------------------------------------------------------------------
// transpose: ch-major [b][C][4096] (ext dtype) -> token-major bf16 rows of
// in_xy [32768][384] (main -> cols 0..255, feat -> cols 256..383).
// ---------------------------------------------------------------------------
__global__ __launch_bounds__(256) void transpose_kernel(
    const void* main_src, const void* feat_src, bf16* __restrict__ dst, const int* flag)
{
    __shared__ float Tt[64*65];
    const int t = threadIdx.x;
    const int p0 = blockIdx.x * 64;
    const int cht = blockIdx.y;
    const int b = blockIdx.z;
    const int f = *flag;

    const void* src; int ch0, srcC, dc0;
    if (cht < 4) { src = main_src; ch0 = cht*64; srcC = 256; dc0 = ch0; }
    else         { src = feat_src; ch0 = (cht-4)*64; srcC = 128; dc0 = 256 + (cht-4)*64; }

    const int p = t & 63, cq = t >> 6;
    #pragma unroll
    for (int e = 0; e < 16; ++e) {
        int c = e*4 + cq;
        Tt[p*65 + c] = lde(src, ((size_t)b*srcC + ch0 + c)*HW + p0 + p, f);
    }
    __syncthreads();
    const int pr = t >> 2, cs = (t & 3) * 16;
    union { uint4 u4[2]; ushort_t us[16]; } pk;
    #pragma unroll
    for (int u = 0; u < 16; ++u) pk.us[u] = f2bu(Tt[pr*65 + cs + u]);
    ushort_t* op = (ushort_t*)dst + ((size_t)b*HW + p0 + pr)*384 + dc0 + cs;
    *(uint4*)op = pk.u4[0];
    *((uint4*)op + 1) = pk.u4[1];
}

// ---------------------------------------------------------------------------
// MFMA GEMM, token-major. A [NTOK][sa] bf16 (k-contig), Bw [M][ldb] bf16.
// OMODE 0: out[tok*sm + m]; 2: out[(tok + 64*(tok>>12))*sm + m] (k_t);
// 1: pos-mode out[((tok>>12)*PROWS + m)*KSTR + tok&4095].
// ---------------------------------------------------------------------------
template<int MT, bool RELU, bool POSEPI, int OMODE>
__global__ __launch_bounds__(256) void gemm_mfma(
    const bf16* __restrict__ A, int sa,
    const bf16* __restrict__ Bw, int ldb,
    const float* __restrict__ bias, const float* __restrict__ posw,
    bf16* __restrict__ out, int sm, int K, float oscale)
{
    const int t = threadIdx.x;
    const int w = t >> 6, lane = t & 63;
    const int n = lane & 15, quad = lane >> 4;
    const int p0 = blockIdx.x * 128;
    const int m0 = blockIdx.y * (MT*16);
    const int rowbase = p0 + w*32;

    f32x4 acc[2][MT];
    #pragma unroll
    for (int pt = 0; pt < 2; ++pt)
        #pragma unroll
        for (int mt = 0; mt < MT; ++mt) acc[pt][mt] = (f32x4){0.f,0.f,0.f,0.f};

    for (int k0 = 0; k0 < K; k0 += 32) {
        bf16x8 ap[2];
        #pragma unroll
        for (int pt = 0; pt < 2; ++pt)
            ap[pt] = *(const bf16x8*)&A[(size_t)(rowbase + pt*16 + n)*sa + k0 + quad*8];
        #pragma unroll
        for (int mt = 0; mt < MT; ++mt) {
            bf16x8 bw = *(const bf16x8*)&Bw[(size_t)(m0 + mt*16 + n)*ldb + k0 + quad*8];
            acc[0][mt] = __builtin_amdgcn_mfma_f32_16x16x32_bf16(ap[0], bw, acc[0][mt], 0, 0, 0);
            acc[1][mt] = __builtin_amdgcn_mfma_f32_16x16x32_bf16(ap[1], bw, acc[1][mt], 0, 0, 0);
        }
    }

    #pragma unroll
    for (int mt = 0; mt < MT; ++mt) {
        const int m = m0 + mt*16 + n;
        const float bi = bias[m];
        float w0 = 0.f, w1 = 0.f;
        if (POSEPI) { w0 = posw[m*2]; w1 = posw[m*2 + 1]; }
        #pragma unroll
        for (int pt = 0; pt < 2; ++pt) {
            const int tokb = rowbase + pt*16 + quad*4;
            if (OMODE == 1) {
                union { uint2 u2; ushort_t us[4]; } pk;
                #pragma unroll
                for (int r = 0; r < 4; ++r) {
                    float v = acc[pt][mt][r] + bi;
                    if (RELU) v = fmaxf(v, 0.f);
                    pk.us[r] = f2bu(v * oscale);
                }
                size_t oi = ((size_t)(tokb >> 12)*PROWS + m)*KSTR + (tokb & 4095);
                *(uint2*)((ushort_t*)out + oi) = pk.u2;
            } else {
                #pragma unroll
                for (int r = 0; r < 4; ++r) {
                    int tok = tokb + r;
                    float v = acc[pt][mt][r] + bi;
                    if (POSEPI) {
                        float gx1 = 2.f * (float)(tok & 63) / 63.f;
                        float gy1 = 2.f * (float)((tok >> 6) & 63) / 63.f;
                        v += w0*gx1 + w1*gy1;
                    }
                    if (RELU) v = fmaxf(v, 0.f);
                    v *= oscale;
                    size_t row = (OMODE == 2) ? (size_t)tok + 64*(size_t)(tok >> 12) : (size_t)tok;
                    out[row*sm + m] = __float2bfloat16(v);
                }
            }
        }
    }
}

// ---------------------------------------------------------------------------
// depthwise 3x3 SAME + bias, token-major bf16.
// ---------------------------------------------------------------------------
__global__ __launch_bounds__(256) void dw_kernel(
    const bf16* __restrict__ in, const bf16* __restrict__ dwt,
    const float* __restrict__ dwb, bf16* __restrict__ out)
{
    const int t = threadIdx.x;
    const int tok = blockIdx.x*8 + (t >> 5);
    const int c8 = (t & 31) * 8;
    const int b = tok >> 12, p = tok & 4095;
    const int i = p >> 6, j = p & 63;

    float acc[8];
    #pragma unroll
    for (int u = 0; u < 8; ++u) acc[u] = dwb[c8 + u];

    #pragma unroll
    for (int di = 0; di < 3; ++di) {
        int ii = i + di - 1;
        if (ii < 0 || ii >= 64) continue;
        #pragma unroll
        for (int dj = 0; dj < 3; ++dj) {
            int jj = j + dj - 1;
            if (jj < 0 || jj >= 64) continue;
            int tok2 = (b << 12) + ii*64 + jj;
            bf16x8 xv = *(const bf16x8*)&in[(size_t)tok2*256 + c8];
            bf16x8 wv = *(const bf16x8*)&dwt[(di*3 + dj)*256 + c8];
            #pragma unroll
            for (int u = 0; u < 8; ++u) acc[u] += (float)xv[u] * (float)wv[u];
        }
    }
    union { uint4 u4; ushort_t us[8]; } pk;
    #pragma unroll
    for (int u = 0; u < 8; ++u) pk.us[u] = f2bu(acc[u]);
    *(uint4*)((ushort_t*)out + (size_t)tok*256 + c8) = pk.u4;
}

// ---------------------------------------------------------------------------
// fill_late: k dustbin token row.
// ---------------------------------------------------------------------------
__global__ __launch_bounds__(256) void fill_late_kernel(
    const void* dvec, bf16* __restrict__ k_t, const int* flag)
{
    const int b = blockIdx.x, t = threadIdx.x;
    k_t[((size_t)b*KSTR + 4096)*256 + t] = __float2bfloat16(lde(dvec, t, *flag));
}

// ---------------------------------------------------------------------------
// MFMA flash attention v8: swapped QK^T + packed P + embedded-P LDS.
// All MFMA/fragment layouts are the PROVEN K=32 ones (v6-verified).
//   * 4 waves; each wave owns a 16-token k-slice of a 64-tok tile in QK^T
//     and holds ALL 64 block q-rows in regs (aq[4]) -> zero-duplication K
//     reads, 4 MFMA per ds_read_b128.
//   * swapped QK^T: sacc = mfma(K_slice, Q) -> D[k-local][q]: lane n holds
//     P for q-col n, k = quad*4+r contiguous -> P packs to ONE b64 write
//     per qf (4/wave/iter vs v6's 16 scalar writes), via proven f2bu.
//   * P embeds into the CONSUMED K-slice region of the current Ks buffer
//     (wave ks writes only the 8KB region whose K rows it alone read; the
//     P values data-depend on all its QK reads -> write cannot pass reads).
//     Block LDS = 64K Ks + 12K posb = 76 KB -> 2 blocks/CU.
//   * barrier2 is lgkmcnt-only (staged next-tile loads stay in flight).
//   * PV: v6's exact K=32 path; wave handles q-rows w*16..+15 over 64 k.
// Sync skeleton identical to verified v6: vmcnt(0)+barrier per tile,
// STAGE(t+1) after the barrier (same race-freedom argument).
// No-max softmax via exp2 (log2e pre-folded into q); l via ones-row (ch 34).
// b = bid&7 pins each batch to one XCD.
// ---------------------------------------------------------------------------
__global__ __launch_bounds__(256, 2) void attn_kernel(
    const bf16* __restrict__ q_t, const bf16* __restrict__ k_t,
    const bf16* __restrict__ pos, void* outv, const int* flag)
{
    __shared__ __align__(16) __bf16 Ks[2*16384];   // 2 bufs x (64 tok x 32 chunks x 16B), swizzled; P embeds after QK
    __shared__ __align__(16) __bf16 posb[2*3072];  // 2 bufs x (48 rows x 8 chunks x 16B), swizzled

    const int t = threadIdx.x;
    const int w = t >> 6, lane = t & 63;          // 4 waves = 4 k-slices
    const int n = lane & 15, quad = lane >> 4;
    const int bid = blockIdx.x;
    const int b = bid & 7;          // batch == XCD id (round-robin dispatch)
    const int qt = bid >> 3;        // 0..63, 64 q-rows per block
    const int ks = w;               // this wave's 16-token k-slice
    const int xw = n & 7;           // read-side swizzle key

    // Q: all 64 block q-rows in registers per wave (4 fragments)
    bf16x8 aq[4][8];
    #pragma unroll
    for (int qf = 0; qf < 4; ++qf) {
        size_t qrow = (size_t)b*HW + qt*64 + qf*16 + n;
        #pragma unroll
        for (int c = 0; c < 8; ++c)
            aq[qf][c] = *(const bf16x8*)&q_t[qrow*256 + c*32 + quad*8];
    }

    // per-wave PV accumulator: q-rows w*16..+15 x 48 ch
    f32x4 pacc[3];
    #pragma unroll
    for (int ct = 0; ct < 3; ++ct) pacc[ct] = (f32x4){0.f,0.f,0.f,0.f};

    const ushort_t* ksrc0 = (const ushort_t*)k_t + (size_t)b*KSTR*256;
    const ushort_t* psrc0 = (const ushort_t*)pos + (size_t)b*PROWS*KSTR;

    // per-wave stage of 64-tok tile: 8 K loads (all waves) + 2 pos loads (waves 0..2)
    auto STAGE = [&](int kt2, int bufn) {
        const int kb = kt2 * 64;
        __bf16* kd = &Ks[(size_t)bufn*16384];
        #pragma unroll
        for (int e = 0; e < 8; ++e) {
            int slot = w*512 + e*64 + lane;          // 0..2047
            int tok = slot >> 5;
            int ch = ((slot & 31) ^ (tok & 7)) * 8;
            async_cp16(&ksrc0[(size_t)(kb + tok)*256 + ch], &kd[(size_t)slot*8]);
        }
        if (w < 3) {
            #pragma unroll
            for (int e = 0; e < 2; ++e) {
                int slot = w*128 + e*64 + lane;      // 0..383 (48 rows x 8 chunks)
                int row = slot >> 3;
                int ch = ((slot & 7) ^ (row & 7)) * 8;
                async_cp16(&psrc0[(size_t)row*KSTR + kb + ch], &posb[(size_t)(bufn*3072 + slot*8)]);
            }
        }
    };

    STAGE(0, 0);
    for (int kt = 0; kt < 65; ++kt) {
        const int cur = kt & 1;
        asm volatile("s_waitcnt vmcnt(0)" ::: "memory");   // STAGE(kt) landed
        __builtin_amdgcn_s_barrier();
        asm volatile("" ::: "memory");
        if (kt + 1 < 65) STAGE(kt + 1, cur ^ 1);           // safe: all passed barrier(kt)

        __bf16* kb_ = &Ks[(size_t)cur*16384];
        const __bf16* pb_ = &posb[(size_t)cur*3072];

        // QK^T swapped: sacc[qf] = K_slice x Q -> D[k-local][q]
        // (proven K=32 fragments: A rows = lane&15 -> tokens ks*16+n,
        //  B cols = lane&15 -> q-rows qf*16+n, D row=quad*4+r, col=n)
        f32x4 sacc[4];
        #pragma unroll
        for (int qf = 0; qf < 4; ++qf) sacc[qf] = (f32x4){0.f,0.f,0.f,0.f};
        #pragma unroll
        for (int c = 0; c < 8; ++c) {
            bf16x8 bk = *(const bf16x8*)&kb_[(size_t)((ks*16 + n)*32 + ((c*4 + quad) ^ xw))*8];
            #pragma unroll
            for (int qf = 0; qf < 4; ++qf)
                sacc[qf] = __builtin_amdgcn_mfma_f32_16x16x32_bf16(bk, aq[qf][c], sacc[qf], 0, 0, 0);
        }

        // P = exp2(s), masked, packed b64 into own k-slice region of kb_.
        // Region [ks*4096, ks*4096+4096) held K tokens only THIS wave read;
        // P values depend on all those reads -> no WAR hazard. Layout:
        // P[q][klocal] row-major, row = 16 bf16 (32 B).
        const int tokb = kt*64 + ks*16 + quad*4;
        #pragma unroll
        for (int qf = 0; qf < 4; ++qf) {
            union { uint2 u2; ushort_t us[4]; } pk;
            #pragma unroll
            for (int r = 0; r < 4; ++r) {
                float e = __builtin_amdgcn_exp2f(sacc[qf][r]);
                pk.us[r] = f2bu((tokb + r <= 4096) ? e : 0.f);
            }
            *(uint2*)&kb_[(size_t)ks*4096 + (qf*16 + n)*16 + quad*4] = pk.u2;
        }

        // barrier2: P visible block-wide (lgkm only -- vm stays in flight)
        asm volatile("s_waitcnt lgkmcnt(0)" ::: "memory");
        __builtin_amdgcn_s_barrier();
        asm volatile("" ::: "memory");

        // PV (v6's proven K=32 path): this wave's 16 q-rows over all 64 k.
        // A k = c*32 + quad*8 + i lives in slice s = c*2+(quad>>1) at
        // offset (quad&1)*8 -- 8 contiguous bf16, 16B-aligned.
        #pragma unroll
        for (int c = 0; c < 2; ++c) {
            int s = c*2 + (quad >> 1);
            bf16x8 aP = *(const bf16x8*)&kb_[(size_t)s*4096 + (w*16 + n)*16 + (quad & 1)*8];
            #pragma unroll
            for (int ct = 0; ct < 3; ++ct) {
                bf16x8 bp = *(const bf16x8*)&pb_[(size_t)((ct*16 + n)*8 + ((c*4 + quad) ^ xw))*8];
                pacc[ct] = __builtin_amdgcn_mfma_f32_16x16x32_bf16(aP, bp, pacc[ct], 0, 0, 0);
            }
        }
    }

    // epilogue: per-wave (no cross-wave reduction). l = ch 34 (ct 2, n 2).
    const int f32o = *flag;
    float linv[4];
    #pragma unroll
    for (int r = 0; r < 4; ++r)
        linv[r] = 1.f / __shfl(pacc[2][r], (lane & 48) | 2, 64);
    #pragma unroll
    for (int ct = 0; ct < 3; ++ct) {
        int ch = ct*16 + n;
        if (ch >= 34) continue;
        #pragma unroll
        for (int r = 0; r < 4; ++r) {
            float v = pacc[ct][r] * linv[r];
            size_t oi = ((size_t)b*34 + ch)*HW + qt*64 + w*16 + quad*4 + r;
            if (f32o) ((float*)outv)[oi] = v;
            else      ((bf16*)outv)[oi]  = __float2bfloat16(v);
        }
    }
}

// ---------------------------------------------------------------------------
extern "C" void kernel_launch(void* const* d_in, const int* in_sizes, int n_in,
                              void* d_out, int out_size, void* d_ws, size_t ws_size,
                              hipStream_t stream)
{
    const void* x      = d_in[0];
    const void* y      = d_in[1];
    const void* feat1  = d_in[2];
    const void* feat2  = d_in[3];
    const void* pg_w1  = d_in[4];
    const void* pg_b1  = d_in[5];
    const void* pg_w2  = d_in[6];
    const void* pg_b2  = d_in[7];
    const void* fus_w1 = d_in[8];
    const void* fus_b1 = d_in[9];
    const void* fus_w2 = d_in[10];
    const void* fus_b2 = d_in[11];
    const void* dw_w   = d_in[12];
    const void* dw_b   = d_in[13];
    const void* pw_w   = d_in[14];
    const void* pw_b   = d_in[15];
    const void* dvec   = d_in[16];
    const void* dpos   = d_in[17];

    // ---- workspace layout (~64 MB) ----
    char* wsb = (char*)d_ws;
    int*  flag = (int*)wsb;
    size_t off = 16;
    bf16* R1   = (bf16*)(wsb + off); off += (size_t)NTOK*384*2;        // in_xy / yf / k_t
    bf16* bufH = (bf16*)(wsb + off); off += (size_t)NTOK*256*2;        // hx / h1 / hy / dwv
    bf16* q_t  = (bf16*)(wsb + off); off += (size_t)NTOK*256*2;
    bf16* pos  = (bf16*)(wsb + off); off += (size_t)NB*PROWS*KSTR*2;
    WsPtrs W;
    W.fw1t  = (bf16*)(wsb + off); off += 98304*2;
    W.fw2t  = (bf16*)(wsb + off); off += 65536*2;
    W.pwt   = (bf16*)(wsb + off); off += 65536*2;
    W.pgw1t = (bf16*)(wsb + off); off += 16384*2;
    W.pgw2t = (bf16*)(wsb + off); off += 4096*2;
    W.dwt   = (bf16*)(wsb + off); off += 2304*2;
    W.pos   = pos;
    W.posw  = (float*)(wsb + off); off += 256*4;
    W.fb1   = (float*)(wsb + off); off += 256*4;
    W.fb2   = (float*)(wsb + off); off += 256*4;
    W.pwb   = (float*)(wsb + off); off += 256*4;
    W.pgb1  = (float*)(wsb + off); off += 128*4;
    W.pgb2  = (float*)(wsb + off); off += 32*4;
    W.dwb   = (float*)(wsb + off); off += 256*4;

    bf16* in_xy = R1;
    bf16* yf    = R1;            // after in_xy dead
    bf16* k_t   = R1;            // after yf dead (row stride KSTR)

    dim3 b256(256);

    // 0. dtype detect + weight/pos prep
    detect_kernel<<<1, 256, 0, stream>>>((const ushort_t*)x, flag);
    prep_kernel<<<1024, b256, 0, stream>>>(fus_w1, fus_w2, pw_w, pg_w1, pg_w2, dw_w,
                                           fus_b1, fus_b2, pw_b, pg_b1, pg_b2, dw_b,
                                           dpos, W, flag);
    // 1. x-phase: transpose(x,feat1) -> in_xy; F1x -> bufH; F2x -> q_t (scaled)
    transpose_kernel<<<dim3(64,6,NB), b256, 0, stream>>>(x, feat1, in_xy, flag);
    gemm_mfma<8, true, false, 0><<<dim3(256,2), b256, 0, stream>>>(
        in_xy, 384, W.fw1t, 384, W.fb1, nullptr, bufH, 256, 384, 1.f);
    gemm_mfma<8, false, false, 0><<<dim3(256,2), b256, 0, stream>>>(
        bufH, 256, W.fw2t, 256, W.fb2, nullptr, q_t, 256, 256, QSCALE);
    // 2. y-phase: transpose(y,feat2) -> in_xy
    transpose_kernel<<<dim3(64,6,NB), b256, 0, stream>>>(y, feat2, in_xy, flag);
    // 3. posgen: L1 (feat2 cols, meshgrid epilogue) -> bufH; L2 -> pos rows 0..31
    gemm_mfma<8, true, true, 0><<<dim3(256,1), b256, 0, stream>>>(
        in_xy + 256, 384, W.pgw1t, 128, W.pgb1, W.posw, bufH, 128, 128, 1.f);
    gemm_mfma<2, true, false, 1><<<dim3(256,1), b256, 0, stream>>>(
        bufH, 128, W.pgw2t, 128, W.pgb2, nullptr, pos, 0, 128, 1.f);
    // 4. fuser-y: L1 -> bufH; L2 -> yf (R1)
    gemm_mfma<8, true, false, 0><<<dim3(256,2), b256, 0, stream>>>(
        in_xy, 384, W.fw1t, 384, W.fb1, nullptr, bufH, 256, 384, 1.f);
    gemm_mfma<8, false, false, 0><<<dim3(256,2), b256, 0, stream>>>(
        bufH, 256, W.fw2t, 256, W.fb2, nullptr, yf, 256, 256, 1.f);
    // 5. depthwise: yf -> bufH (dwv)
    dw_kernel<<<dim3(4096), b256, 0, stream>>>(yf, W.dwt, W.dwb, bufH);
    // 6. k dustbin, then pointwise: bufH -> k_t (KSTR rows)
    fill_late_kernel<<<dim3(NB), b256, 0, stream>>>(dvec, k_t, flag);
    gemm_mfma<8, false, false, 2><<<dim3(256,2), b256, 0, stream>>>(
        bufH, 256, W.pwt, 256, W.pwb, nullptr, k_t, 256, 256, 1.f);
    // 7. attention
    attn_kernel<<<dim3(512), b256, 0, stream>>>(q_t, k_t, pos, d_out, flag);
}

// Round 16
// 466.745 us; speedup vs baseline: 1.1640x; 1.0289x over previous
//
#include <hip/hip_runtime.h>
#include <hip/hip_bf16.h>

typedef __hip_bfloat16 bf16;
typedef unsigned short ushort_t;
typedef __bf16 bf16x8 __attribute__((ext_vector_type(8)));
typedef float  f32x4  __attribute__((ext_vector_type(4)));

#define HW    4096
#define NB    8
#define KSTR  4160     // padded token count for k/pos; token 4096 = dustbin
#define NTOK  32768    // NB*HW
#define PROWS 64       // padded pos channel rows (34 real + ones@34 + zeros, 48..63 slack)
#define QSCALE 0.0901684400557f   // (1/16) * log2(e): folds exp->exp2

__device__ __forceinline__ float lde(const void* p, size_t i, int f32f) {
    return f32f ? ((const float*)p)[i] : (float)((const bf16*)p)[i];
}
__device__ __forceinline__ ushort_t f2bu(float f){ union { __bf16 b; ushort_t u; } cv; cv.b = (__bf16)f; return cv.u; }

__device__ __forceinline__ void async_cp16(const void* g, void* l) {
    __builtin_amdgcn_global_load_lds(
        (const __attribute__((address_space(1))) unsigned int*)g,
        (__attribute__((address_space(3))) unsigned int*)l, 16, 0, 0);
}

// ---------------------------------------------------------------------------
// dtype detector: flag=1 if inputs are float32, 0 if bf16.
// ---------------------------------------------------------------------------
__global__ void detect_kernel(const ushort_t* xb, int* flag)
{
    __shared__ int cnt;
    const int t = threadIdx.x;
    if (t == 0) cnt = 0;
    __syncthreads();
    ushort_t h = xb[2*t];
    int e = (h >> 7) & 0xFF;
    if (e >= 133) atomicAdd(&cnt, 1);
    __syncthreads();
    if (t == 0) *flag = (cnt > 8) ? 1 : 0;
}

// ---------------------------------------------------------------------------
// prep: weights/biases -> bf16/f32 ws copies; dw taps transposed; pos fixed
// rows (mesh 32/33, ones 34, zeros 35..47, dustbin col 4096, ztail 4097+).
// ---------------------------------------------------------------------------
struct WsPtrs {
    bf16 *fw1t, *fw2t, *pwt, *pgw1t, *pgw2t, *dwt, *pos;
    float *posw, *fb1, *fb2, *pwb, *pgb1, *pgb2, *dwb;
};

__global__ __launch_bounds__(256) void prep_kernel(
    const void* fus_w1, const void* fus_w2, const void* pw_w,
    const void* pg_w1, const void* pg_w2, const void* dw_w,
    const void* fus_b1, const void* fus_b2, const void* pw_b,
    const void* pg_b1, const void* pg_b2, const void* dw_b,
    const void* dpos, WsPtrs W, const int* flag)
{
    const int f = *flag;
    const long n_w1 = 98304, n_w2 = 65536, n_pw = 65536, n_g1 = 16384, n_g2 = 4096;
    const long n_posw = 256, n_dwt = 2304;
    const long n_b = 256, n_gb1 = 128, n_gb2 = 32;
    const long n_mesh = 65536;            // rows 32/33, tok 0..4095
    const long n_pad  = 8L*14*KSTR;       // rows 34..47 (34=ones) all cols
    const long n_dust = 272;              // rows 0..33 col 4096
    const long n_zt   = 8L*34*63;         // rows 0..33 cols 4097..4159
    const long total = n_w1+n_w2+n_pw+n_g1+n_g2+n_posw+n_dwt
                     + 3*n_b + n_gb1 + n_gb2 + n_b + n_mesh + n_pad + n_dust + n_zt;

    for (long i = blockIdx.x*256L + threadIdx.x; i < total; i += gridDim.x*256L) {
        long j = i;
        if (j < n_w1) { W.fw1t[j] = __float2bfloat16(lde(fus_w1, j, f)); continue; } j -= n_w1;
        if (j < n_w2) { W.fw2t[j] = __float2bfloat16(lde(fus_w2, j, f)); continue; } j -= n_w2;
        if (j < n_pw) { W.pwt[j]  = __float2bfloat16(lde(pw_w,  j, f)); continue; } j -= n_pw;
        if (j < n_g1) { W.pgw1t[j] = __float2bfloat16(lde(pg_w1, (j>>7)*130 + 2 + (j&127), f)); continue; } j -= n_g1;
        if (j < n_g2) { W.pgw2t[j] = __float2bfloat16(lde(pg_w2, j, f)); continue; } j -= n_g2;
        if (j < n_posw) { W.posw[j] = lde(pg_w1, (j>>1)*130 + (j&1), f); continue; } j -= n_posw;
        if (j < n_dwt) { W.dwt[j] = __float2bfloat16(lde(dw_w, (j&255)*9 + (j>>8), f)); continue; } j -= n_dwt;
        if (j < n_b)   { W.fb1[j] = lde(fus_b1, j, f); continue; } j -= n_b;
        if (j < n_b)   { W.fb2[j] = lde(fus_b2, j, f); continue; } j -= n_b;
        if (j < n_b)   { W.pwb[j] = lde(pw_b, j, f); continue; } j -= n_b;
        if (j < n_gb1) { W.pgb1[j] = lde(pg_b1, j, f); continue; } j -= n_gb1;
        if (j < n_gb2) { W.pgb2[j] = lde(pg_b2, j, f); continue; } j -= n_gb2;
        if (j < n_b)   { W.dwb[j] = lde(dw_b, j, f); continue; } j -= n_b;
        if (j < n_mesh) {
            long b = j >> 13; int rr = (int)((j>>12)&1); int tok = (int)(j & 4095);
            float v = rr ? (-1.f + 2.f*(float)((tok>>6)&63)/63.f)
                         : (-1.f + 2.f*(float)(tok&63)/63.f);
            W.pos[((size_t)b*PROWS + 32 + rr)*KSTR + tok] = __float2bfloat16(v);
            continue;
        } j -= n_mesh;
        if (j < n_pad) {
            long b = j / (14L*KSTR); long rem = j % (14L*KSTR);
            int row = 34 + (int)(rem / KSTR); int tok = (int)(rem % KSTR);
            W.pos[((size_t)b*PROWS + row)*KSTR + tok] = __float2bfloat16(row == 34 ? 1.f : 0.f);
            continue;
        } j -= n_pad;
        if (j < n_dust) {
            long b = j / 34; int ch = (int)(j % 34);
            W.pos[((size_t)b*PROWS + ch)*KSTR + 4096] = __float2bfloat16(lde(dpos, ch, f));
            continue;
        } j -= n_dust;
        { long b = j / (34*63); long rem = j % (34*63);
          int ch = (int)(rem / 63); int cc = (int)(rem % 63);
          W.pos[((size_t)b*PROWS + ch)*KSTR + 4097 + cc] = __float2bfloat16(0.f); }
    }
}

// ---------------------------------------------------------------------------
// transpose: ch-major [b][C][4096] (ext dtype) -> token-major bf16 rows of
// in_xy [32768][384] (main -> cols 0..255, feat -> cols 256..383).
// ---------------------------------------------------------------------------
__global__ __launch_bounds__(256) void transpose_kernel(
    const void* main_src, const void* feat_src, bf16* __restrict__ dst, const int* flag)
{
    __shared__ float Tt[64*65];
    const int t = threadIdx.x;
    const int p0 = blockIdx.x * 64;
    const int cht = blockIdx.y;
    const int b = blockIdx.z;
    const int f = *flag;

    const void* src; int ch0, srcC, dc0;
    if (cht < 4) { src = main_src; ch0 = cht*64; srcC = 256; dc0 = ch0; }
    else         { src = feat_src; ch0 = (cht-4)*64; srcC = 128; dc0 = 256 + (cht-4)*64; }

    const int p = t & 63, cq = t >> 6;
    #pragma unroll
    for (int e = 0; e < 16; ++e) {
        int c = e*4 + cq;
        Tt[p*65 + c] = lde(src, ((size_t)b*srcC + ch0 + c)*HW + p0 + p, f);
    }
    __syncthreads();
    const int pr = t >> 2, cs = (t & 3) * 16;
    union { uint4 u4[2]; ushort_t us[16]; } pk;
    #pragma unroll
    for (int u = 0; u < 16; ++u) pk.us[u] = f2bu(Tt[pr*65 + cs + u]);
    ushort_t* op = (ushort_t*)dst + ((size_t)b*HW + p0 + pr)*384 + dc0 + cs;
    *(uint4*)op = pk.u4[0];
    *((uint4*)op + 1) = pk.u4[1];
}

// ---------------------------------------------------------------------------
// MFMA GEMM, token-major. A [NTOK][sa] bf16 (k-contig), Bw [M][ldb] bf16.
// OMODE 0: out[tok*sm + m]; 2: out[(tok + 64*(tok>>12))*sm + m] (k_t);
// 1: pos-mode out[((tok>>12)*PROWS + m)*KSTR + tok&4095].
// ---------------------------------------------------------------------------
template<int MT, bool RELU, bool POSEPI, int OMODE>
__global__ __launch_bounds__(256) void gemm_mfma(
    const bf16* __restrict__ A, int sa,
    const bf16* __restrict__ Bw, int ldb,
    const float* __restrict__ bias, const float* __restrict__ posw,
    bf16* __restrict__ out, int sm, int K, float oscale)
{
    const int t = threadIdx.x;
    const int w = t >> 6, lane = t & 63;
    const int n = lane & 15, quad = lane >> 4;
    const int p0 = blockIdx.x * 128;
    const int m0 = blockIdx.y * (MT*16);
    const int rowbase = p0 + w*32;

    f32x4 acc[2][MT];
    #pragma unroll
    for (int pt = 0; pt < 2; ++pt)
        #pragma unroll
        for (int mt = 0; mt < MT; ++mt) acc[pt][mt] = (f32x4){0.f,0.f,0.f,0.f};

    for (int k0 = 0; k0 < K; k0 += 32) {
        bf16x8 ap[2];
        #pragma unroll
        for (int pt = 0; pt < 2; ++pt)
            ap[pt] = *(const bf16x8*)&A[(size_t)(rowbase + pt*16 + n)*sa + k0 + quad*8];
        #pragma unroll
        for (int mt = 0; mt < MT; ++mt) {
            bf16x8 bw = *(const bf16x8*)&Bw[(size_t)(m0 + mt*16 + n)*ldb + k0 + quad*8];
            acc[0][mt] = __builtin_amdgcn_mfma_f32_16x16x32_bf16(ap[0], bw, acc[0][mt], 0, 0, 0);
            acc[1][mt] = __builtin_amdgcn_mfma_f32_16x16x32_bf16(ap[1], bw, acc[1][mt], 0, 0, 0);
        }
    }

    #pragma unroll
    for (int mt = 0; mt < MT; ++mt) {
        const int m = m0 + mt*16 + n;
        const float bi = bias[m];
        float w0 = 0.f, w1 = 0.f;
        if (POSEPI) { w0 = posw[m*2]; w1 = posw[m*2 + 1]; }
        #pragma unroll
        for (int pt = 0; pt < 2; ++pt) {
            const int tokb = rowbase + pt*16 + quad*4;
            if (OMODE == 1) {
                union { uint2 u2; ushort_t us[4]; } pk;
                #pragma unroll
                for (int r = 0; r < 4; ++r) {
                    float v = acc[pt][mt][r] + bi;
                    if (RELU) v = fmaxf(v, 0.f);
                    pk.us[r] = f2bu(v * oscale);
                }
                size_t oi = ((size_t)(tokb >> 12)*PROWS + m)*KSTR + (tokb & 4095);
                *(uint2*)((ushort_t*)out + oi) = pk.u2;
            } else {
                #pragma unroll
                for (int r = 0; r < 4; ++r) {
                    int tok = tokb + r;
                    float v = acc[pt][mt][r] + bi;
                    if (POSEPI) {
                        float gx1 = 2.f * (float)(tok & 63) / 63.f;
                        float gy1 = 2.f * (float)((tok >> 6) & 63) / 63.f;
                        v += w0*gx1 + w1*gy1;
                    }
                    if (RELU) v = fmaxf(v, 0.f);
                    v *= oscale;
                    size_t row = (OMODE == 2) ? (size_t)tok + 64*(size_t)(tok >> 12) : (size_t)tok;
                    out[row*sm + m] = __float2bfloat16(v);
                }
            }
        }
    }
}

// ---------------------------------------------------------------------------
// depthwise 3x3 SAME + bias, token-major bf16.
// ---------------------------------------------------------------------------
__global__ __launch_bounds__(256) void dw_kernel(
    const bf16* __restrict__ in, const bf16* __restrict__ dwt,
    const float* __restrict__ dwb, bf16* __restrict__ out)
{
    const int t = threadIdx.x;
    const int tok = blockIdx.x*8 + (t >> 5);
    const int c8 = (t & 31) * 8;
    const int b = tok >> 12, p = tok & 4095;
    const int i = p >> 6, j = p & 63;

    float acc[8];
    #pragma unroll
    for (int u = 0; u < 8; ++u) acc[u] = dwb[c8 + u];

    #pragma unroll
    for (int di = 0; di < 3; ++di) {
        int ii = i + di - 1;
        if (ii < 0 || ii >= 64) continue;
        #pragma unroll
        for (int dj = 0; dj < 3; ++dj) {
            int jj = j + dj - 1;
            if (jj < 0 || jj >= 64) continue;
            int tok2 = (b << 12) + ii*64 + jj;
            bf16x8 xv = *(const bf16x8*)&in[(size_t)tok2*256 + c8];
            bf16x8 wv = *(const bf16x8*)&dwt[(di*3 + dj)*256 + c8];
            #pragma unroll
            for (int u = 0; u < 8; ++u) acc[u] += (float)xv[u] * (float)wv[u];
        }
    }
    union { uint4 u4; ushort_t us[8]; } pk;
    #pragma unroll
    for (int u = 0; u < 8; ++u) pk.us[u] = f2bu(acc[u]);
    *(uint4*)((ushort_t*)out + (size_t)tok*256 + c8) = pk.u4;
}

// ---------------------------------------------------------------------------
// fill_late: k dustbin token row.
// ---------------------------------------------------------------------------
__global__ __launch_bounds__(256) void fill_late_kernel(
    const void* dvec, bf16* __restrict__ k_t, const int* flag)
{
    const int b = blockIdx.x, t = threadIdx.x;
    k_t[((size_t)b*KSTR + 4096)*256 + t] = __float2bfloat16(lde(dvec, t, *flag));
}

// ---------------------------------------------------------------------------
// MFMA flash attention v9: v8 (verified) + P-swizzle + hoisted STAGE addrs +
// last-tile-only masking.
// Round-13 counters on v8: bank conflicts UP (1.07e7, ~640cy/CU/iter) from
// the embedded-P path (P-write was 8-way: 16 banks for 128 touches), and
// VALUBusy 34% from per-iter STAGE addressing + masked exp2.
//   * P layout now K-style swizzled: row q = 8 chunk-slots of 16B, slot
//     chunk^(q&7) -> write = uniform 4-way (b64 floor), read = b128 floor.
//   * STAGE per-lane offsets hoisted out of the k-loop (pointer bump only).
//   * Mask applied only at kt==64 (uniform branch).
// Everything else identical to v8: swapped QK^T (verified), embedded P in
// the consumed K-slice, lgkm-only barrier2, vmcnt(0) staging skeleton,
// b = bid&7 XCD pinning, l via ones-row (ch 34).
// ---------------------------------------------------------------------------
__global__ __launch_bounds__(256, 2) void attn_kernel(
    const bf16* __restrict__ q_t, const bf16* __restrict__ k_t,
    const bf16* __restrict__ pos, void* outv, const int* flag)
{
    __shared__ __align__(16) __bf16 Ks[2*16384];   // 2 bufs x (64 tok x 32 chunks x 16B), swizzled; P embeds after QK
    __shared__ __align__(16) __bf16 posb[2*3072];  // 2 bufs x (48 rows x 8 chunks x 16B), swizzled

    const int t = threadIdx.x;
    const int w = t >> 6, lane = t & 63;          // 4 waves = 4 k-slices
    const int n = lane & 15, quad = lane >> 4;
    const int bid = blockIdx.x;
    const int b = bid & 7;          // batch == XCD id (round-robin dispatch)
    const int qt = bid >> 3;        // 0..63, 64 q-rows per block
    const int ks = w;               // this wave's 16-token k-slice
    const int xw = n & 7;           // read-side swizzle key

    // Q: all 64 block q-rows in registers per wave (4 fragments)
    bf16x8 aq[4][8];
    #pragma unroll
    for (int qf = 0; qf < 4; ++qf) {
        size_t qrow = (size_t)b*HW + qt*64 + qf*16 + n;
        #pragma unroll
        for (int c = 0; c < 8; ++c)
            aq[qf][c] = *(const bf16x8*)&q_t[qrow*256 + c*32 + quad*8];
    }

    // per-wave PV accumulator: q-rows w*16..+15 x 48 ch
    f32x4 pacc[3];
    #pragma unroll
    for (int ct = 0; ct < 3; ++ct) pacc[ct] = (f32x4){0.f,0.f,0.f,0.f};

    const ushort_t* ksrc0 = (const ushort_t*)k_t + (size_t)b*KSTR*256;
    const ushort_t* psrc0 = (const ushort_t*)pos + (size_t)b*PROWS*KSTR;

    // hoisted per-lane STAGE offsets (loop-invariant): 8 K + 2 pos
    int koff[8], kslot[8];
    #pragma unroll
    for (int e = 0; e < 8; ++e) {
        int slot = w*512 + e*64 + lane;          // 0..2047
        int tok = slot >> 5;
        int ch = ((slot & 31) ^ (tok & 7)) * 8;
        koff[e] = tok*256 + ch;
        kslot[e] = slot*8;
    }
    int poff[2], pslot[2];
    #pragma unroll
    for (int e = 0; e < 2; ++e) {
        int slot = w*128 + e*64 + lane;          // 0..383 used (w<3)
        int row = slot >> 3;
        int ch = ((slot & 7) ^ (row & 7)) * 8;
        poff[e] = row*KSTR + ch;
        pslot[e] = slot*8;
    }

    // per-wave stage of 64-tok tile kt2 into buffer bufn
    auto STAGE = [&](int kt2, int bufn) {
        const ushort_t* kc = ksrc0 + (size_t)kt2*(64*256);
        __bf16* kd = &Ks[(size_t)bufn*16384];
        #pragma unroll
        for (int e = 0; e < 8; ++e)
            async_cp16(&kc[koff[e]], &kd[kslot[e]]);
        if (w < 3) {
            const ushort_t* pc = psrc0 + kt2*64;
            __bf16* pd = &posb[(size_t)bufn*3072];
            #pragma unroll
            for (int e = 0; e < 2; ++e)
                async_cp16(&pc[poff[e]], &pd[pslot[e]]);
        }
    };

    STAGE(0, 0);
    for (int kt = 0; kt < 65; ++kt) {
        const int cur = kt & 1;
        asm volatile("s_waitcnt vmcnt(0)" ::: "memory");   // STAGE(kt) landed
        __builtin_amdgcn_s_barrier();
        asm volatile("" ::: "memory");
        if (kt + 1 < 65) STAGE(kt + 1, cur ^ 1);           // safe: all passed barrier(kt)

        __bf16* kb_ = &Ks[(size_t)cur*16384];
        const __bf16* pb_ = &posb[(size_t)cur*3072];

        // QK^T swapped: sacc[qf] = K_slice x Q -> D[k-local][q]
        f32x4 sacc[4];
        #pragma unroll
        for (int qf = 0; qf < 4; ++qf) sacc[qf] = (f32x4){0.f,0.f,0.f,0.f};
        #pragma unroll
        for (int c = 0; c < 8; ++c) {
            bf16x8 bk = *(const bf16x8*)&kb_[(size_t)((ks*16 + n)*32 + ((c*4 + quad) ^ xw))*8];
            #pragma unroll
            for (int qf = 0; qf < 4; ++qf)
                sacc[qf] = __builtin_amdgcn_mfma_f32_16x16x32_bf16(bk, aq[qf][c], sacc[qf], 0, 0, 0);
        }

        // P = exp2(s), packed b64 into own k-slice region (K-style swizzle:
        // row q = 8 slots of 16B, slot = chunk ^ (q&7); chunk = quad>>1,
        // half = quad&1). Mask only the final tile (uniform branch).
        #pragma unroll
        for (int qf = 0; qf < 4; ++qf) {
            union { uint2 u2; ushort_t us[4]; } pk;
            if (kt < 64) {
                #pragma unroll
                for (int r = 0; r < 4; ++r)
                    pk.us[r] = f2bu(__builtin_amdgcn_exp2f(sacc[qf][r]));
            } else {
                const int tokb = kt*64 + ks*16 + quad*4;
                #pragma unroll
                for (int r = 0; r < 4; ++r) {
                    float e = __builtin_amdgcn_exp2f(sacc[qf][r]);
                    pk.us[r] = f2bu((tokb + r <= 4096) ? e : 0.f);
                }
            }
            *(uint2*)&kb_[(size_t)ks*4096 + (size_t)((qf*16 + n)*8 + ((quad >> 1) ^ xw))*8 + (quad & 1)*4] = pk.u2;
        }

        // barrier2: P visible block-wide (lgkm only -- vm stays in flight)
        asm volatile("s_waitcnt lgkmcnt(0)" ::: "memory");
        __builtin_amdgcn_s_barrier();
        asm volatile("" ::: "memory");

        // PV: this wave's 16 q-rows over all 64 k. A k-chunk for klocal
        // (quad&1)*8..+7 in slice s = c*2+(quad>>1): slot (quad&1)^(q&7).
        #pragma unroll
        for (int c = 0; c < 2; ++c) {
            int s = c*2 + (quad >> 1);
            bf16x8 aP = *(const bf16x8*)&kb_[(size_t)s*4096 + (size_t)((w*16 + n)*8 + ((quad & 1) ^ xw))*8];
            #pragma unroll
            for (int ct = 0; ct < 3; ++ct) {
                bf16x8 bp = *(const bf16x8*)&pb_[(size_t)((ct*16 + n)*8 + ((c*4 + quad) ^ xw))*8];
                pacc[ct] = __builtin_amdgcn_mfma_f32_16x16x32_bf16(aP, bp, pacc[ct], 0, 0, 0);
            }
        }
    }

    // epilogue: per-wave (no cross-wave reduction). l = ch 34 (ct 2, n 2).
    const int f32o = *flag;
    float linv[4];
    #pragma unroll
    for (int r = 0; r < 4; ++r)
        linv[r] = 1.f / __shfl(pacc[2][r], (lane & 48) | 2, 64);
    #pragma unroll
    for (int ct = 0; ct < 3; ++ct) {
        int ch = ct*16 + n;
        if (ch >= 34) continue;
        #pragma unroll
        for (int r = 0; r < 4; ++r) {
            float v = pacc[ct][r] * linv[r];
            size_t oi = ((size_t)b*34 + ch)*HW + qt*64 + w*16 + quad*4 + r;
            if (f32o) ((float*)outv)[oi] = v;
            else      ((bf16*)outv)[oi]  = __float2bfloat16(v);
        }
    }
}

// ---------------------------------------------------------------------------
extern "C" void kernel_launch(void* const* d_in, const int* in_sizes, int n_in,
                              void* d_out, int out_size, void* d_ws, size_t ws_size,
                              hipStream_t stream)
{
    const void* x      = d_in[0];
    const void* y      = d_in[1];
    const void* feat1  = d_in[2];
    const void* feat2  = d_in[3];
    const void* pg_w1  = d_in[4];
    const void* pg_b1  = d_in[5];
    const void* pg_w2  = d_in[6];
    const void* pg_b2  = d_in[7];
    const void* fus_w1 = d_in[8];
    const void* fus_b1 = d_in[9];
    const void* fus_w2 = d_in[10];
    const void* fus_b2 = d_in[11];
    const void* dw_w   = d_in[12];
    const void* dw_b   = d_in[13];
    const void* pw_w   = d_in[14];
    const void* pw_b   = d_in[15];
    const void* dvec   = d_in[16];
    const void* dpos   = d_in[17];

    // ---- workspace layout (~64 MB) ----
    char* wsb = (char*)d_ws;
    int*  flag = (int*)wsb;
    size_t off = 16;
    bf16* R1   = (bf16*)(wsb + off); off += (size_t)NTOK*384*2;        // in_xy / yf / k_t
    bf16* bufH = (bf16*)(wsb + off); off += (size_t)NTOK*256*2;        // hx / h1 / hy / dwv
    bf16* q_t  = (bf16*)(wsb + off); off += (size_t)NTOK*256*2;
    bf16* pos  = (bf16*)(wsb + off); off += (size_t)NB*PROWS*KSTR*2;
    WsPtrs W;
    W.fw1t  = (bf16*)(wsb + off); off += 98304*2;
    W.fw2t  = (bf16*)(wsb + off); off += 65536*2;
    W.pwt   = (bf16*)(wsb + off); off += 65536*2;
    W.pgw1t = (bf16*)(wsb + off); off += 16384*2;
    W.pgw2t = (bf16*)(wsb + off); off += 4096*2;
    W.dwt   = (bf16*)(wsb + off); off += 2304*2;
    W.pos   = pos;
    W.posw  = (float*)(wsb + off); off += 256*4;
    W.fb1   = (float*)(wsb + off); off += 256*4;
    W.fb2   = (float*)(wsb + off); off += 256*4;
    W.pwb   = (float*)(wsb + off); off += 256*4;
    W.pgb1  = (float*)(wsb + off); off += 128*4;
    W.pgb2  = (float*)(wsb + off); off += 32*4;
    W.dwb   = (float*)(wsb + off); off += 256*4;

    bf16* in_xy = R1;
    bf16* yf    = R1;            // after in_xy dead
    bf16* k_t   = R1;            // after yf dead (row stride KSTR)

    dim3 b256(256);

    // 0. dtype detect + weight/pos prep
    detect_kernel<<<1, 256, 0, stream>>>((const ushort_t*)x, flag);
    prep_kernel<<<1024, b256, 0, stream>>>(fus_w1, fus_w2, pw_w, pg_w1, pg_w2, dw_w,
                                           fus_b1, fus_b2, pw_b, pg_b1, pg_b2, dw_b,
                                           dpos, W, flag);
    // 1. x-phase: transpose(x,feat1) -> in_xy; F1x -> bufH; F2x -> q_t (scaled)
    transpose_kernel<<<dim3(64,6,NB), b256, 0, stream>>>(x, feat1, in_xy, flag);
    gemm_mfma<8, true, false, 0><<<dim3(256,2), b256, 0, stream>>>(
        in_xy, 384, W.fw1t, 384, W.fb1, nullptr, bufH, 256, 384, 1.f);
    gemm_mfma<8, false, false, 0><<<dim3(256,2), b256, 0, stream>>>(
        bufH, 256, W.fw2t, 256, W.fb2, nullptr, q_t, 256, 256, QSCALE);
    // 2. y-phase: transpose(y,feat2) -> in_xy
    transpose_kernel<<<dim3(64,6,NB), b256, 0, stream>>>(y, feat2, in_xy, flag);
    // 3. posgen: L1 (feat2 cols, meshgrid epilogue) -> bufH; L2 -> pos rows 0..31
    gemm_mfma<8, true, true, 0><<<dim3(256,1), b256, 0, stream>>>(
        in_xy + 256, 384, W.pgw1t, 128, W.pgb1, W.posw, bufH, 128, 128, 1.f);
    gemm_mfma<2, true, false, 1><<<dim3(256,1), b256, 0, stream>>>(
        bufH, 128, W.pgw2t, 128, W.pgb2, nullptr, pos, 0, 128, 1.f);
    // 4. fuser-y: L1 -> bufH; L2 -> yf (R1)
    gemm_mfma<8, true, false, 0><<<dim3(256,2), b256, 0, stream>>>(
        in_xy, 384, W.fw1t, 384, W.fb1, nullptr, bufH, 256, 384, 1.f);
    gemm_mfma<8, false, false, 0><<<dim3(256,2), b256, 0, stream>>>(
        bufH, 256, W.fw2t, 256, W.fb2, nullptr, yf, 256, 256, 1.f);
    // 5. depthwise: yf -> bufH (dwv)
    dw_kernel<<<dim3(4096), b256, 0, stream>>>(yf, W.dwt, W.dwb, bufH);
    // 6. k dustbin, then pointwise: bufH -> k_t (KSTR rows)
    fill_late_kernel<<<dim3(NB), b256, 0, stream>>>(dvec, k_t, flag);
    gemm_mfma<8, false, false, 2><<<dim3(256,2), b256, 0, stream>>>(
        bufH, 256, W.pwt, 256, W.pwb, nullptr, k_t, 256, 256, 1.f);
    // 7. attention
    attn_kernel<<<dim3(512), b256, 0, stream>>>(q_t, k_t, pos, d_out, flag);
}